// Round 24
// baseline (334.648 us; speedup 1.0000x reference)
//
#include <hip/hip_runtime.h>
#include <stdint.h>
#include <math.h>

#define EMB       256
#define D_INNER   512
#define HEADDIM   64
#define NHEADS    8
#define DSTATE    128
#define DCONV     4
#define CONV_DIM  768
#define LN_EPS    1e-5f
#define NBATCH    64
#define SEQLEN    512
#define NTOK      (NBATCH*SEQLEN)   // 32768

typedef __attribute__((ext_vector_type(8))) short          short8;
typedef __attribute__((ext_vector_type(8))) unsigned short u16x8;
typedef __attribute__((ext_vector_type(4))) unsigned short u16x4;
typedef __attribute__((ext_vector_type(4))) float          f32x4;

__device__ __forceinline__ float bfb(unsigned short u) {
    union { unsigned int i; float f; } x; x.i = ((unsigned int)u) << 16; return x.f;
}
__device__ __forceinline__ unsigned short fbf(float f) {
    union { float f; unsigned int i; } x; x.f = f;
    unsigned int i = x.i;
    unsigned int lsb = (i >> 16) & 1u;
    i += 0x7fffu + lsb;
    return (unsigned short)(i >> 16);
}

// async global->LDS 16B
__device__ __forceinline__ void gld16(const unsigned short* g, unsigned short* l) {
    __builtin_amdgcn_global_load_lds((const __attribute__((address_space(1))) void*)g,
                                     (__attribute__((address_space(3))) void*)l, 16, 0, 0);
}

// ---------------- merged f32->bf16 converts (inW | outW) ----------------
__global__ __launch_bounds__(256) void cvt2_k(const float* __restrict__ a, unsigned short* __restrict__ oa, int na,
                                              const float* __restrict__ b, unsigned short* __restrict__ ob, int nb) {
    int i = blockIdx.x * 256 + threadIdx.x;
    if (i < na) oa[i] = fbf(a[i]);
    else { i -= na; if (i < nb) ob[i] = fbf(b[i]); }
}

// ---------------- merged weight-norm x3 ----------------
__global__ __launch_bounds__(256) void wnorm3_k(const float* __restrict__ g0, const float* __restrict__ v0, unsigned short* __restrict__ o0,
                                                const float* __restrict__ g1, const float* __restrict__ v1, unsigned short* __restrict__ o1,
                                                const float* __restrict__ g2, const float* __restrict__ v2, unsigned short* __restrict__ o2) {
    int o = blockIdx.x & 255, s = blockIdx.x >> 8, tid = threadIdx.x;
    const float* g = s == 0 ? g0 : (s == 1 ? g1 : g2);
    const float* v = s == 0 ? v0 : (s == 1 ? v1 : v2);
    unsigned short* wout = s == 0 ? o0 : (s == 1 ? o1 : o2);
    float x = v[(size_t)o * 256 + tid];
    float q = x * x;
    __shared__ float sm[4];
    #pragma unroll
    for (int d = 32; d; d >>= 1) q += __shfl_down(q, d);
    if ((tid & 63) == 0) sm[tid >> 6] = q;
    __syncthreads();
    float tot = sm[0] + sm[1] + sm[2] + sm[3];
    float scale = g[o] * rsqrtf(tot);
    wout[(size_t)o * 256 + tid] = fbf(x * scale);
}

// ---------------- Wco = wff @ outW  (256x512) ----------------
__global__ __launch_bounds__(256) void wco_k(const unsigned short* __restrict__ wff,
                                             const unsigned short* __restrict__ outWb,
                                             unsigned short* __restrict__ wco) {
    int i = blockIdx.x, tid = threadIdx.x;
    __shared__ float row[256];
    row[tid] = bfb(wff[(size_t)i * 256 + tid]);
    __syncthreads();
    #pragma unroll
    for (int half = 0; half < 2; half++) {
        int k = tid + half * 256;
        float acc = 0.f;
        for (int j = 0; j < 256; j++)
            acc += row[j] * bfb(outWb[(size_t)j * 512 + k]);
        wco[(size_t)i * 512 + k] = fbf(acc);
    }
}

// ---------------- LayerNorm (256-wide), f32 in -> bf16 out ----------------
__global__ __launch_bounds__(256) void ln_k(const float* __restrict__ in,
                                            const float* __restrict__ w,
                                            const float* __restrict__ b,
                                            unsigned short* __restrict__ out) {
    int tok = blockIdx.x, tid = threadIdx.x;
    size_t idx = (size_t)tok * 256 + tid;
    float x = in[idx];
    __shared__ float sm[8];
    float s = x;
    #pragma unroll
    for (int o = 32; o; o >>= 1) s += __shfl_down(s, o);
    if ((tid & 63) == 0) sm[tid >> 6] = s;
    __syncthreads();
    float mean = (sm[0] + sm[1] + sm[2] + sm[3]) * (1.f / 256.f);
    float d = x - mean;
    float q = d * d;
    #pragma unroll
    for (int o = 32; o; o >>= 1) q += __shfl_down(q, o);
    if ((tid & 63) == 0) sm[4 + (tid >> 6)] = q;
    __syncthreads();
    float var = (sm[4] + sm[5] + sm[6] + sm[7]) * (1.f / 256.f);
    out[idx] = fbf(d * rsqrtf(var + LN_EPS) * w[tid] + b[tid]);
}

// ---------------- MFMA GEMM v4b (unchanged from r23) ----------------
#define BMT 128
#define BNT 128
#define BKT 32
template<int EPI, int NBN>
__global__ __launch_bounds__(256, 2) void gemm_k(const unsigned short* __restrict__ A,
                                                 const unsigned short* __restrict__ Bw,
                                                 int K, int N,
                                                 unsigned short* __restrict__ out_b,
                                                 float* __restrict__ out_f,
                                                 const float* __restrict__ bias,
                                                 const float* __restrict__ res_f,
                                                 unsigned short* __restrict__ out2_b) {
    __shared__ __align__(16) unsigned short smem[16384];
    int tid = threadIdx.x;
    int d = blockIdx.x;
    const int cpx = (256 * NBN) >> 3;
    int logical = (d & 7) * cpx + (d >> 3);
    int bm = logical / NBN;
    int bn = logical % NBN;
    int lane = tid & 63, w = tid >> 6;
    int wr = w >> 1, wc = w & 1;
    int fr = lane & 15, fq = lane >> 4;

    int rsub = w * 16 + (lane >> 2);
    int cl   = ((lane & 3) ^ ((rsub >> 1) & 3)) << 3;
    const unsigned short* gA0 = A  + (size_t)(bm * BMT + rsub)      * K + cl;
    const unsigned short* gA1 = A  + (size_t)(bm * BMT + rsub + 64) * K + cl;
    const unsigned short* gB0 = Bw + (size_t)(bn * BNT + rsub)      * K + cl;
    const unsigned short* gB1 = Bw + (size_t)(bn * BNT + rsub + 64) * K + cl;

    f32x4 acc[4][4];
    #pragma unroll
    for (int m = 0; m < 4; m++)
        #pragma unroll
        for (int n = 0; n < 4; n++)
            #pragma unroll
            for (int r = 0; r < 4; r++) acc[m][n][r] = 0.f;

    auto AS = [&](int buf) { return &smem[buf * 4096]; };
    auto BS = [&](int buf) { return &smem[8192 + buf * 4096]; };
    auto STAGE = [&](int buf, int k0) {
        gld16(gA0 + k0, AS(buf) + w * 512);
        gld16(gA1 + k0, AS(buf) + 2048 + w * 512);
        gld16(gB0 + k0, BS(buf) + w * 512);
        gld16(gB1 + k0, BS(buf) + 2048 + w * 512);
    };

    int nt = K / BKT;
    STAGE(0, 0);
    STAGE(1, BKT);
    for (int t = 0; t < nt; ++t) {
        int buf = t & 1;
        if (t < nt - 1) asm volatile("s_waitcnt vmcnt(4)" ::: "memory");
        else            asm volatile("s_waitcnt vmcnt(0)" ::: "memory");
        __builtin_amdgcn_s_barrier();
        short8 af[4], bf_[4];
        #pragma unroll
        for (int m = 0; m < 4; m++) {
            int ra = wr * 64 + m * 16 + fr;
            af[m] = *(const short8*)&AS(buf)[ra * 32 + ((fq ^ ((ra >> 1) & 3)) << 3)];
        }
        #pragma unroll
        for (int n = 0; n < 4; n++) {
            int rb = wc * 64 + n * 16 + fr;
            bf_[n] = *(const short8*)&BS(buf)[rb * 32 + ((fq ^ ((rb >> 1) & 3)) << 3)];
        }
        asm volatile("s_waitcnt lgkmcnt(0)" ::: "memory");
        __builtin_amdgcn_sched_barrier(0);
        __builtin_amdgcn_s_barrier();
        if (t + 2 < nt) STAGE(buf, (t + 2) * BKT);
        __builtin_amdgcn_s_setprio(1);
        #pragma unroll
        for (int m = 0; m < 4; m++)
            #pragma unroll
            for (int n = 0; n < 4; n++)
                acc[m][n] = __builtin_amdgcn_mfma_f32_16x16x32_bf16(af[m], bf_[n], acc[m][n], 0, 0, 0);
        __builtin_amdgcn_s_setprio(0);
    }
    __builtin_amdgcn_s_barrier();

    if (EPI == 1 && bn == 10) {
        #pragma unroll
        for (int m = 0; m < 4; m++)
            #pragma unroll
            for (int n = 0; n < 4; n++)
                #pragma unroll
                for (int r = 0; r < 4; r++) {
                    int grow = bm * BMT + wr * 64 + m * 16 + fq * 4 + r;
                    int gcol = 1280 + wc * 64 + n * 16 + fr;
                    if (gcol < 1288) {
                        float a2 = acc[m][n][r] + bias[gcol - 1280];
                        out_f[(size_t)grow * 8 + (gcol - 1280)] =
                            a2 > 20.f ? a2 : log1pf(expf(a2));
                    }
                }
    } else if (EPI == 0 || EPI == 1) {
        unsigned short* cb = smem;
        #pragma unroll
        for (int s = 0; s < 2; s++) {
            if (wr == s) {
                #pragma unroll
                for (int m = 0; m < 4; m++)
                    #pragma unroll
                    for (int n = 0; n < 4; n++)
                        #pragma unroll
                        for (int r = 0; r < 4; r++)
                            cb[(m * 16 + fq * 4 + r) * 136 + wc * 64 + n * 16 + fr] =
                                fbf(acc[m][n][r]);
            }
            __syncthreads();
            #pragma unroll
            for (int k = 0; k < 4; k++) {
                int g = k * 256 + tid;
                int row = g >> 4, col = (g & 15) << 3;
                u16x8 v = *(const u16x8*)&cb[row * 136 + col];
                int grow = bm * BMT + s * 64 + row;
                int gc = bn * BNT + col;
                if (EPI == 0) {
                    *(u16x8*)&out_b[(size_t)grow * N + gc] = v;
                } else {
                    if (gc < 512) *(u16x8*)&out_b[(size_t)grow * 512 + gc] = v;
                    else          *(u16x8*)&out2_b[(size_t)grow * 768 + (gc - 512)] = v;
                }
            }
            __syncthreads();
        }
    } else {
        float* fb = (float*)smem;
        #pragma unroll
        for (int s = 0; s < 4; s++) {
            if (wr == (s >> 1)) {
                int mp = s & 1;
                #pragma unroll
                for (int mm = 0; mm < 2; mm++)
                    #pragma unroll
                    for (int n = 0; n < 4; n++)
                        #pragma unroll
                        for (int r = 0; r < 4; r++)
                            fb[(mm * 16 + fq * 4 + r) * 132 + wc * 64 + n * 16 + fr] =
                                acc[mp * 2 + mm][n][r];
            }
            __syncthreads();
            #pragma unroll
            for (int k = 0; k < 4; k++) {
                int g = k * 256 + tid;
                int row = g >> 5, col = (g & 31) << 2;
                f32x4 v = *(const f32x4*)&fb[row * 132 + col];
                int grow = bm * BMT + (s >> 1) * 64 + (s & 1) * 32 + row;
                int gc = bn * BNT + col;
                size_t idx = (size_t)grow * 256 + gc;
                if (EPI == 2) {
                    f32x4 rr = *(const f32x4*)&res_f[idx];
                    f32x4 o;
                    #pragma unroll
                    for (int j = 0; j < 4; j++) o[j] = rr[j] + v[j] + bias[gc + j];
                    *(f32x4*)&out_f[idx] = o;
                } else {
                    u16x4 o;
                    #pragma unroll
                    for (int j = 0; j < 4; j++) {
                        float x = v[j] + bias[gc + j];
                        o[j] = fbf(0.5f * x * (1.f + erff(x * 0.70710678118654752f)));
                    }
                    *(u16x4*)&out_b[idx] = o;
                }
            }
            __syncthreads();
        }
    }
}

// ---------------- halo save ----------------
__global__ __launch_bounds__(256) void halo_k(const unsigned short* __restrict__ xbc,
                                              unsigned short* __restrict__ halo) {
    int blk = blockIdx.x;
    int b = blk / 3, c = blk % 3 + 1;
    int tid = threadIdx.x;
    for (int i = tid; i < 288; i += 256) {
        int j = i / 96, off = (i % 96) * 8;
        size_t tok = (size_t)b * 512 + c * 128 - 3 + j;
        *(u16x8*)&halo[((size_t)(b * 4 + c) * 3 + j) * 768 + off] =
            *(const u16x8*)&xbc[tok * 768 + off];
    }
}

// ---------------- causal depthwise conv4 + bias + silu, PARALLEL (halo) ----------------
__global__ __launch_bounds__(256) void conv_k(unsigned short* xbc,
                                              const unsigned short* __restrict__ halo,
                                              const float* __restrict__ cw,
                                              const float* __restrict__ cb) {
    int b  = blockIdx.y;
    int c  = blockIdx.z;
    int c0 = blockIdx.x * 64;
    int t0 = c * 128;
    int tid = threadIdx.x;
    int cth = tid & 63;
    int rq  = tid >> 6;
    __shared__ unsigned short sraw[131][72];

    int ca = c0 + cth;
    float w0 = cw[ca * 4 + 0], w1 = cw[ca * 4 + 1];
    float w2 = cw[ca * 4 + 2], w3 = cw[ca * 4 + 3];
    float bias = cb[ca];

    if (tid < 192) {
        int j = tid >> 6, cc = tid & 63;
        sraw[j][cc] = (c == 0) ? (unsigned short)0
            : halo[((size_t)(b * 4 + c) * 3 + j) * 768 + c0 + cc];
    }
    for (int idx = tid; idx < 1024; idx += 256) {
        int lt = idx >> 3, cg = idx & 7;
        *(u16x8*)&sraw[3 + lt][cg * 8] =
            *(const u16x8*)&xbc[((size_t)(b * 512 + t0 + lt)) * 768 + c0 + cg * 8];
    }
    __syncthreads();
    #pragma unroll 4
    for (int i = 0; i < 32; i++) {
        int lt = rq + 4 * i;
        float acc = bias
            + bfb(sraw[lt + 0][cth]) * w0
            + bfb(sraw[lt + 1][cth]) * w1
            + bfb(sraw[lt + 2][cth]) * w2
            + bfb(sraw[lt + 3][cth]) * w3;
        acc = acc / (1.f + expf(-acc));
        xbc[((size_t)(b * 512 + t0 + lt)) * 768 + c0 + cth] = fbf(acc);
    }
}

#define CPAD 136
#define TPAD 56
#define TOFF(r) ((((r) >> 4) & 3) << 3)

// ---------------- SSD v5 (r22, 512-block fallback) ----------------
__global__ __launch_bounds__(256) void ssd_k(const unsigned short* __restrict__ xc,
                                             const float* __restrict__ dts,
                                             const float* __restrict__ A_log,
                                             const float* __restrict__ D_param,
                                             unsigned short* __restrict__ y) {
    __shared__ unsigned short Ct[32][CPAD];
    __shared__ unsigned short Bt[32][CPAD];
    __shared__ unsigned short BtT[128][TPAD];
    __shared__ unsigned short DXT[64][TPAD];
    __shared__ unsigned short LG[32][40];
    __shared__ unsigned short hB[64][CPAD];
    __shared__ unsigned short Yb[32][72];
    __shared__ float scum[32], sdt2[32], sEC[32];
    __shared__ float sET[32][36];

    int d = blockIdx.x;
    int b = (d & 7) | (((d >> 6) & 7) << 3);
    int h = (d >> 3) & 7;
    int tid = threadIdx.x;
    int w = tid >> 6;
    int lane = tid & 63;
    int fr = lane & 15, fq = lane >> 4;

    float A_h = -expf(A_log[h]);
    float D_h = D_param[h];

    f32x4 hacc[8];
    #pragma unroll
    for (int nf = 0; nf < 8; nf++)
        #pragma unroll
        for (int r = 0; r < 4; r++) hacc[nf][r] = 0.f;

    int t  = tid >> 3;
    int e8 = tid & 7;

    u16x8 bv0, bv1, cv0, cv1, xv;
    {
        const unsigned short* row = &xc[((size_t)b * 512 + t) * 768];
        bv0 = *(const u16x8*)&row[512 + e8 * 16];
        bv1 = *(const u16x8*)&row[512 + e8 * 16 + 8];
        cv0 = *(const u16x8*)&row[640 + e8 * 16];
        cv1 = *(const u16x8*)&row[640 + e8 * 16 + 8];
        xv  = *(const u16x8*)&row[h * 64 + e8 * 8];
    }

    for (int c = 0; c < 16; ++c) {
        size_t tok0 = (size_t)b * 512 + c * 32;
        *(u16x8*)&Ct[t][e8 * 16]     = cv0;
        *(u16x8*)&Ct[t][e8 * 16 + 8] = cv1;
        *(u16x8*)&Bt[t][e8 * 16]     = bv0;
        *(u16x8*)&Bt[t][e8 * 16 + 8] = bv1;
        if (tid < 32) {
            float dtv = dts[(tok0 + tid) * 8 + h];
            sdt2[tid] = dtv;
            float la = dtv * A_h;
            #pragma unroll
            for (int dd = 1; dd < 32; dd <<= 1) {
                float up = __shfl_up(la, dd);
                if (lane >= dd) la += up;
            }
            scum[tid] = la;
        }
        __syncthreads();
        float cumQ = scum[31];
        if (tid < 32) sEC[tid] = expf(scum[tid]);
        {
            float dtv = sdt2[t];
            float wgt = expf(cumQ - scum[t]);
            int tof = TOFF(e8 * 16);
            #pragma unroll
            for (int j = 0; j < 8; j++) {
                float dtx = dtv * bfb(xv[j]);
                int rr = e8 * 8 + j;
                DXT[rr][t + TOFF(rr)] = fbf(dtx);
                BtT[e8 * 16 + j][t + tof]     = fbf(wgt * bfb(bv0[j]));
                BtT[e8 * 16 + 8 + j][t + tof] = fbf(wgt * bfb(bv1[j]));
            }
        }
        #pragma unroll
        for (int k = 0; k < 4; k++) {
            int idx = tid * 4 + k;
            int tt = idx >> 5, tq = idx & 31;
            sET[tt][tq] = (tq <= tt) ? expf(scum[tt] - scum[tq]) : 0.f;
        }
        #pragma unroll
        for (int nf = 0; nf < 8; nf++)
            #pragma unroll
            for (int r = 0; r < 4; r++)
                hB[w * 16 + fq * 4 + r][nf * 16 + fr] = fbf(hacc[nf][r]);
        u16x8 nbv0, nbv1, ncv0, ncv1, nxv;
        {
            size_t ptok = (c + 1 < 16) ? (tok0 + 32 + t) : (tok0 + t);
            const unsigned short* row = &xc[ptok * 768];
            nbv0 = *(const u16x8*)&row[512 + e8 * 16];
            nbv1 = *(const u16x8*)&row[512 + e8 * 16 + 8];
            ncv0 = *(const u16x8*)&row[640 + e8 * 16];
            ncv1 = *(const u16x8*)&row[640 + e8 * 16 + 8];
            nxv  = *(const u16x8*)&row[h * 64 + e8 * 8];
        }
        __syncthreads();
        {
            int m = w >> 1, nf = w & 1;
            f32x4 g;
            #pragma unroll
            for (int r = 0; r < 4; r++) g[r] = 0.f;
            #pragma unroll
            for (int ks = 0; ks < 4; ks++) {
                short8 ca = *(const short8*)&Ct[m * 16 + fr][ks * 32 + fq * 8];
                short8 bb = *(const short8*)&Bt[nf * 16 + fr][ks * 32 + fq * 8];
                g = __builtin_amdgcn_mfma_f32_16x16x32_bf16(ca, bb, g, 0, 0, 0);
            }
            #pragma unroll
            for (int r = 0; r < 4; r++) {
                int tt = m * 16 + fq * 4 + r;
                int tq = nf * 16 + fr;
                LG[tt][tq] = fbf(g[r] * sET[tt][tq]);
            }
        }
        __syncthreads();
        f32x4 Yi[2];
        #pragma unroll
        for (int m = 0; m < 2; m++)
            #pragma unroll
            for (int r = 0; r < 4; r++) Yi[m][r] = 0.f;
        #pragma unroll
        for (int ks = 0; ks < 4; ks++) {
            short8 a0 = *(const short8*)&Ct[fr][ks * 32 + fq * 8];
            short8 a1 = *(const short8*)&Ct[16 + fr][ks * 32 + fq * 8];
            short8 hb = *(const short8*)&hB[w * 16 + fr][ks * 32 + fq * 8];
            Yi[0] = __builtin_amdgcn_mfma_f32_16x16x32_bf16(a0, hb, Yi[0], 0, 0, 0);
            Yi[1] = __builtin_amdgcn_mfma_f32_16x16x32_bf16(a1, hb, Yi[1], 0, 0, 0);
        }
        #pragma unroll
        for (int m = 0; m < 2; m++)
            #pragma unroll
            for (int r = 0; r < 4; r++) Yi[m][r] *= sEC[m * 16 + fq * 4 + r];
        {
            int wof = TOFF(w * 16);
            short8 a0 = *(const short8*)&LG[fr][fq * 8];
            short8 a1 = *(const short8*)&LG[16 + fr][fq * 8];
            short8 dx = *(const short8*)&DXT[w * 16 + fr][fq * 8 + wof];
            Yi[0] = __builtin_amdgcn_mfma_f32_16x16x32_bf16(a0, dx, Yi[0], 0, 0, 0);
            Yi[1] = __builtin_amdgcn_mfma_f32_16x16x32_bf16(a1, dx, Yi[1], 0, 0, 0);
        }
        {
            float ecq = sEC[31];
            #pragma unroll
            for (int nf = 0; nf < 8; nf++)
                #pragma unroll
                for (int r = 0; r < 4; r++) hacc[nf][r] *= ecq;
            int wof = TOFF(w * 16);
            short8 ax = *(const short8*)&DXT[w * 16 + fr][fq * 8 + wof];
            #pragma unroll
            for (int nf = 0; nf < 8; nf++) {
                short8 bb = *(const short8*)&BtT[nf * 16 + fr][fq * 8 + TOFF(nf * 16)];
                hacc[nf] = __builtin_amdgcn_mfma_f32_16x16x32_bf16(ax, bb, hacc[nf], 0, 0, 0);
            }
        }
        #pragma unroll
        for (int m = 0; m < 2; m++)
            #pragma unroll
            for (int r = 0; r < 4; r++) {
                int tt = m * 16 + fq * 4 + r;
                Yb[tt][w * 16 + fr] = fbf(Yi[m][r]);
            }
        __syncthreads();
        {
            u16x8 yv = *(const u16x8*)&Yb[t][e8 * 8];
            u16x8 ov;
            #pragma unroll
            for (int j = 0; j < 8; j++)
                ov[j] = fbf(bfb(yv[j]) + D_h * bfb(xv[j]));
            *(u16x8*)&y[(tok0 + t) * 512 + h * 64 + e8 * 8] = ov;
        }
        bv0 = nbv0; bv1 = nbv1; cv0 = ncv0; cv1 = ncv1; xv = nxv;
    }
}

// ---------------- SSD v6: DSTATE-split, 1024 blocks = (b, h, state-half) ----------------
// Y = Y_half0 + Y_half1 (summed in gate2_k). ph==0 also adds D*x.
#define CPAD2 72
__global__ __launch_bounds__(256) void ssd2_k(const unsigned short* __restrict__ xc,
                                              const float* __restrict__ dts,
                                              const float* __restrict__ A_log,
                                              const float* __restrict__ D_param,
                                              unsigned short* __restrict__ y0,
                                              unsigned short* __restrict__ y1) {
    __shared__ unsigned short Ct[32][CPAD2];
    __shared__ unsigned short Bt[32][CPAD2];
    __shared__ unsigned short BtT[64][TPAD];   // 64 local states
    __shared__ unsigned short DXT[64][TPAD];   // full 64 p
    __shared__ unsigned short LG[32][40];
    __shared__ unsigned short hB[64][CPAD2];   // [p][64 states]
    __shared__ unsigned short Yb[32][72];
    __shared__ float scum[32], sdt2[32], sEC[32];
    __shared__ float sET[32][36];

    int d = blockIdx.x;                         // 10 bits: b_lo(3) h(3) ph(1) b_hi(3)
    int b  = (d & 7) | (((d >> 7) & 7) << 3);
    int h  = (d >> 3) & 7;
    int ph = (d >> 6) & 1;
    int n0 = ph << 6;                           // state offset 0 / 64
    unsigned short* yo = ph ? y1 : y0;
    int tid = threadIdx.x;
    int w = tid >> 6;
    int lane = tid & 63;
    int fr = lane & 15, fq = lane >> 4;

    float A_h = -expf(A_log[h]);
    float D_h = D_param[h];

    f32x4 hacc[4];
    #pragma unroll
    for (int nf = 0; nf < 4; nf++)
        #pragma unroll
        for (int r = 0; r < 4; r++) hacc[nf][r] = 0.f;

    int t  = tid >> 3;
    int e8 = tid & 7;

    // prologue loads (8 B-elems + 8 C-elems of this half, 8 x-elems)
    u16x8 bv, cv, xv;
    {
        const unsigned short* row = &xc[((size_t)b * 512 + t) * 768];
        bv = *(const u16x8*)&row[512 + n0 + e8 * 8];
        cv = *(const u16x8*)&row[640 + n0 + e8 * 8];
        xv = *(const u16x8*)&row[h * 64 + e8 * 8];
    }

    for (int c = 0; c < 16; ++c) {
        size_t tok0 = (size_t)b * 512 + c * 32;
        // Phase A
        *(u16x8*)&Ct[t][e8 * 8] = cv;
        *(u16x8*)&Bt[t][e8 * 8] = bv;
        if (tid < 32) {
            float dtv = dts[(tok0 + tid) * 8 + h];
            sdt2[tid] = dtv;
            float la = dtv * A_h;
            #pragma unroll
            for (int dd = 1; dd < 32; dd <<= 1) {
                float up = __shfl_up(la, dd);
                if (lane >= dd) la += up;
            }
            scum[tid] = la;
        }
        __syncthreads();
        float cumQ = scum[31];
        // Phase B
        if (tid < 32) sEC[tid] = expf(scum[tid]);
        {
            float dtv = sdt2[t];
            float wgt = expf(cumQ - scum[t]);
            #pragma unroll
            for (int j = 0; j < 8; j++) {
                int rr = e8 * 8 + j;
                DXT[rr][t + TOFF(rr)] = fbf(dtv * bfb(xv[j]));
                BtT[rr][t + TOFF(rr)] = fbf(wgt * bfb(bv[j]));
            }
        }
        #pragma unroll
        for (int k = 0; k < 4; k++) {
            int idx = tid * 4 + k;
            int tt = idx >> 5, tq = idx & 31;
            sET[tt][tq] = (tq <= tt) ? expf(scum[tt] - scum[tq]) : 0.f;
        }
        #pragma unroll
        for (int nf = 0; nf < 4; nf++)
            #pragma unroll
            for (int r = 0; r < 4; r++)
                hB[w * 16 + fq * 4 + r][nf * 16 + fr] = fbf(hacc[nf][r]);
        // prefetch next chunk
        u16x8 nbv, ncv, nxv;
        {
            size_t ptok = (c + 1 < 16) ? (tok0 + 32 + t) : (tok0 + t);
            const unsigned short* row = &xc[ptok * 768];
            nbv = *(const u16x8*)&row[512 + n0 + e8 * 8];
            ncv = *(const u16x8*)&row[640 + n0 + e8 * 8];
            nxv = *(const u16x8*)&row[h * 64 + e8 * 8];
        }
        __syncthreads();
        // Phase C: LG quadrant over K=64
        {
            int m = w >> 1, nf = w & 1;
            f32x4 g;
            #pragma unroll
            for (int r = 0; r < 4; r++) g[r] = 0.f;
            #pragma unroll
            for (int ks = 0; ks < 2; ks++) {
                short8 ca = *(const short8*)&Ct[m * 16 + fr][ks * 32 + fq * 8];
                short8 bb = *(const short8*)&Bt[nf * 16 + fr][ks * 32 + fq * 8];
                g = __builtin_amdgcn_mfma_f32_16x16x32_bf16(ca, bb, g, 0, 0, 0);
            }
            #pragma unroll
            for (int r = 0; r < 4; r++) {
                int tt = m * 16 + fq * 4 + r;
                int tq = nf * 16 + fr;
                LG[tt][tq] = fbf(g[r] * sET[tt][tq]);
            }
        }
        __syncthreads();
        // Phase D
        f32x4 Yi[2];
        #pragma unroll
        for (int m = 0; m < 2; m++)
            #pragma unroll
            for (int r = 0; r < 4; r++) Yi[m][r] = 0.f;
        #pragma unroll
        for (int ks = 0; ks < 2; ks++) {
            short8 a0 = *(const short8*)&Ct[fr][ks * 32 + fq * 8];
            short8 a1 = *(const short8*)&Ct[16 + fr][ks * 32 + fq * 8];
            short8 hb = *(const short8*)&hB[w * 16 + fr][ks * 32 + fq * 8];
            Yi[0] = __builtin_amdgcn_mfma_f32_16x16x32_bf16(a0, hb, Yi[0], 0, 0, 0);
            Yi[1] = __builtin_amdgcn_mfma_f32_16x16x32_bf16(a1, hb, Yi[1], 0, 0, 0);
        }
        #pragma unroll
        for (int m = 0; m < 2; m++)
            #pragma unroll
            for (int r = 0; r < 4; r++) Yi[m][r] *= sEC[m * 16 + fq * 4 + r];
        {
            int wof = TOFF(w * 16);
            short8 a0 = *(const short8*)&LG[fr][fq * 8];
            short8 a1 = *(const short8*)&LG[16 + fr][fq * 8];
            short8 dx = *(const short8*)&DXT[w * 16 + fr][fq * 8 + wof];
            Yi[0] = __builtin_amdgcn_mfma_f32_16x16x32_bf16(a0, dx, Yi[0], 0, 0, 0);
            Yi[1] = __builtin_amdgcn_mfma_f32_16x16x32_bf16(a1, dx, Yi[1], 0, 0, 0);
        }
        {
            float ecq = sEC[31];
            #pragma unroll
            for (int nf = 0; nf < 4; nf++)
                #pragma unroll
                for (int r = 0; r < 4; r++) hacc[nf][r] *= ecq;
            int wof = TOFF(w * 16);
            short8 ax = *(const short8*)&DXT[w * 16 + fr][fq * 8 + wof];
            #pragma unroll
            for (int nf = 0; nf < 4; nf++) {
                short8 bb = *(const short8*)&BtT[nf * 16 + fr][fq * 8 + TOFF(nf * 16)];
                hacc[nf] = __builtin_amdgcn_mfma_f32_16x16x32_bf16(ax, bb, hacc[nf], 0, 0, 0);
            }
        }
        #pragma unroll
        for (int m = 0; m < 2; m++)
            #pragma unroll
            for (int r = 0; r < 4; r++) {
                int tt = m * 16 + fq * 4 + r;
                Yb[tt][w * 16 + fr] = fbf(Yi[m][r]);
            }
        __syncthreads();
        // Phase E: partial-Y store (D*x only in half 0)
        {
            u16x8 yv = *(const u16x8*)&Yb[t][e8 * 8];
            u16x8 ov;
            if (ph == 0) {
                #pragma unroll
                for (int j = 0; j < 8; j++)
                    ov[j] = fbf(bfb(yv[j]) + D_h * bfb(xv[j]));
            } else {
                ov = yv;
            }
            *(u16x8*)&yo[(tok0 + t) * 512 + h * 64 + e8 * 8] = ov;
        }
        bv = nbv; cv = ncv; xv = nxv;
    }
}

// ---------------- gate variants ----------------
template<int TWO>
__global__ __launch_bounds__(256) void gate_k(const unsigned short* __restrict__ y,
                                              const unsigned short* __restrict__ y1,
                                              const unsigned short* __restrict__ zg,
                                              const float* __restrict__ nw,
                                              unsigned short* __restrict__ yn) {
    int tok = blockIdx.x, tid = threadIdx.x;
    size_t base = (size_t)tok * 512;
    float gv[2];
    float q = 0.f;
    #pragma unroll
    for (int j = 0; j < 2; j++) {
        int c = tid + j * 256;
        float yy = bfb(y[base + c]);
        if (TWO) yy += bfb(y1[base + c]);
        float zz = bfb(zg[base + c]);
        float s = zz / (1.f + expf(-zz));
        float t = yy * s;
        gv[j] = t;
        q += t * t;
    }
    __shared__ float sm[4];
    #pragma unroll
    for (int o = 32; o; o >>= 1) q += __shfl_down(q, o);
    if ((tid & 63) == 0) sm[tid >> 6] = q;
    __syncthreads();
    float ms = (sm[0] + sm[1] + sm[2] + sm[3]) * (1.f / 512.f);
    float r = rsqrtf(ms + LN_EPS);
    #pragma unroll
    for (int j = 0; j < 2; j++) {
        int c = tid + j * 256;
        yn[base + c] = fbf(gv[j] * r * nw[c]);
    }
}

extern "C" void kernel_launch(void* const* d_in, const int* in_sizes, int n_in,
                              void* d_out, int out_size, void* d_ws, size_t ws_size,
                              hipStream_t stream) {
    if (n_in < 22) return;
    static const int setup_sizes[22] = {8388608,256,256,329728,3072,768,8,8,8,512,
                                        131072,256,65536,256,256,256,256,65536,256,256,65536,256};
    for (int i = 0; i < 22; i++) if (in_sizes[i] != setup_sizes[i]) return;

    const float* z      = (const float*)d_in[0];
    const float* ln1w   = (const float*)d_in[1];
    const float* ln1b   = (const float*)d_in[2];
    const float* inW    = (const float*)d_in[3];
    const float* convw  = (const float*)d_in[4];
    const float* convb  = (const float*)d_in[5];
    const float* dtb    = (const float*)d_in[6];
    const float* Alog   = (const float*)d_in[7];
    const float* Dp     = (const float*)d_in[8];
    const float* normw  = (const float*)d_in[9];
    const float* outW   = (const float*)d_in[10];
    const float* ffg    = (const float*)d_in[11];
    const float* ffv    = (const float*)d_in[12];
    const float* ffb    = (const float*)d_in[13];
    const float* ln2w   = (const float*)d_in[14];
    const float* ln2b   = (const float*)d_in[15];
    const float* fc1g   = (const float*)d_in[16];
    const float* fc1v   = (const float*)d_in[17];
    const float* fc1b   = (const float*)d_in[18];
    const float* fc2g   = (const float*)d_in[19];
    const float* fc2v   = (const float*)d_in[20];
    const float* fc2b   = (const float*)d_in[21];
    float* out = (float*)d_out;
    (void)out_size;

    char* ws = (char*)d_ws;
    const size_t SLOT_A = (size_t)NTOK * 768 * 2;
    const size_t SLOT_B = (size_t)NTOK * 512 * 2;
    const size_t SLOT_C = (size_t)NTOK * 512 * 2;
    const size_t SLOT_D = (size_t)NTOK * 256 * 2;
    const size_t SLOT_E = (size_t)NTOK * 8 * 4;
    const size_t SLOT_W = (size_t)256 * 256 * 2;
    const size_t SLOT_WI = (size_t)1288 * 256 * 2;
    const size_t SLOT_WO = (size_t)256 * 512 * 2;
    const size_t SLOT_WC = (size_t)256 * 512 * 2;
    const size_t SLOT_H  = (size_t)256 * 3 * 768 * 2;
    const size_t SLOT_Y2 = (size_t)NTOK * 512 * 2;     // partial-Y half 1 (optional)
    char* pA = ws;
    char* pB = pA + SLOT_A;
    char* pC = pB + SLOT_B;
    char* pD = pC + SLOT_C;
    char* pE = pD + SLOT_D;
    char* pW = pE + SLOT_E;
    char* pWI = pW + 3 * SLOT_W;
    char* pWO = pWI + SLOT_WI;
    char* pWC = pWO + SLOT_WO;
    char* pH  = pWC + SLOT_WC;
    char* pY2 = pH + SLOT_H;
    size_t need = SLOT_A + SLOT_B + SLOT_C + SLOT_D + SLOT_E + 3 * SLOT_W + SLOT_WI + SLOT_WO + SLOT_WC + SLOT_H;
    if (ws_size < need) return;
    bool split = (ws_size >= need + SLOT_Y2);

    unsigned short* xbc = (unsigned short*)pA;
    unsigned short* yn  = (unsigned short*)pA;
    unsigned short* t2  = (unsigned short*)(pA + (size_t)NTOK * 512 * 2);
    unsigned short* y   = (unsigned short*)pB;
    float*          z2  = (float*)pB;
    unsigned short* zgb = (unsigned short*)pC;
    unsigned short* u   = (unsigned short*)pD;
    unsigned short* h1  = (unsigned short*)pD;
    float*          dts = (float*)pE;
    unsigned short* wff  = (unsigned short*)pW;
    unsigned short* wfc1 = (unsigned short*)(pW + SLOT_W);
    unsigned short* wfc2 = (unsigned short*)(pW + 2 * SLOT_W);
    unsigned short* inWb = (unsigned short*)pWI;
    unsigned short* outWb = (unsigned short*)pWO;
    unsigned short* wco  = (unsigned short*)pWC;
    unsigned short* halo = (unsigned short*)pH;
    unsigned short* y2   = (unsigned short*)pY2;

    cvt2_k<<<(1288 * 256 + 131072 + 255) / 256, 256, 0, stream>>>(inW, inWb, 1288 * 256,
                                                                  outW, outWb, 131072);
    wnorm3_k<<<768, 256, 0, stream>>>(ffg, ffv, wff, fc1g, fc1v, wfc1, fc2g, fc2v, wfc2);
    wco_k<<<256, 256, 0, stream>>>(wff, outWb, wco);
    ln_k<<<NTOK, 256, 0, stream>>>(z, ln1w, ln1b, u);
    gemm_k<1, 11><<<256 * 11, 256, 0, stream>>>(u, inWb, 256, 1288,
                                                zgb, dts, dtb, nullptr, xbc);
    halo_k<<<192, 256, 0, stream>>>(xbc, halo);
    conv_k<<<dim3(12, 64, 4), 256, 0, stream>>>(xbc, halo, convw, convb);
    if (split) {
        ssd2_k<<<1024, 256, 0, stream>>>(xbc, dts, Alog, Dp, y, y2);
        gate_k<1><<<NTOK, 256, 0, stream>>>(y, y2, zgb, normw, yn);
    } else {
        ssd_k<<<512, 256, 0, stream>>>(xbc, dts, Alog, Dp, y);
        gate_k<0><<<NTOK, 256, 0, stream>>>(y, nullptr, zgb, normw, yn);
    }
    gemm_k<2, 2><<<256 * 2, 256, 0, stream>>>(yn, wco, 512, 256,
                                              nullptr, z2, ffb, z, nullptr);
    ln_k<<<NTOK, 256, 0, stream>>>(z2, ln2w, ln2b, t2);
    gemm_k<3, 2><<<256 * 2, 256, 0, stream>>>(t2, wfc1, 256, 256,
                                              h1, nullptr, fc1b, nullptr, nullptr);
    gemm_k<2, 2><<<256 * 2, 256, 0, stream>>>(h1, wfc2, 256, 256,
                                              nullptr, out, fc2b, z2, nullptr);
}

// Round 25
// 290.327 us; speedup vs baseline: 1.1527x; 1.1527x over previous
//
#include <hip/hip_runtime.h>
#include <stdint.h>
#include <math.h>

#define EMB       256
#define D_INNER   512
#define HEADDIM   64
#define NHEADS    8
#define DSTATE    128
#define DCONV     4
#define CONV_DIM  768
#define LN_EPS    1e-5f
#define NBATCH    64
#define SEQLEN    512
#define NTOK      (NBATCH*SEQLEN)   // 32768

typedef __attribute__((ext_vector_type(8))) short          short8;
typedef __attribute__((ext_vector_type(8))) unsigned short u16x8;
typedef __attribute__((ext_vector_type(4))) unsigned short u16x4;
typedef __attribute__((ext_vector_type(4))) float          f32x4;

__device__ __forceinline__ float bfb(unsigned short u) {
    union { unsigned int i; float f; } x; x.i = ((unsigned int)u) << 16; return x.f;
}
__device__ __forceinline__ unsigned short fbf(float f) {
    union { float f; unsigned int i; } x; x.f = f;
    unsigned int i = x.i;
    unsigned int lsb = (i >> 16) & 1u;
    i += 0x7fffu + lsb;
    return (unsigned short)(i >> 16);
}

// async global->LDS 16B
__device__ __forceinline__ void gld16(const unsigned short* g, unsigned short* l) {
    __builtin_amdgcn_global_load_lds((const __attribute__((address_space(1))) void*)g,
                                     (__attribute__((address_space(3))) void*)l, 16, 0, 0);
}

// ---------------- merged f32->bf16 converts (inW | outW) ----------------
__global__ __launch_bounds__(256) void cvt2_k(const float* __restrict__ a, unsigned short* __restrict__ oa, int na,
                                              const float* __restrict__ b, unsigned short* __restrict__ ob, int nb) {
    int i = blockIdx.x * 256 + threadIdx.x;
    if (i < na) oa[i] = fbf(a[i]);
    else { i -= na; if (i < nb) ob[i] = fbf(b[i]); }
}

// ---------------- merged weight-norm x3 ----------------
__global__ __launch_bounds__(256) void wnorm3_k(const float* __restrict__ g0, const float* __restrict__ v0, unsigned short* __restrict__ o0,
                                                const float* __restrict__ g1, const float* __restrict__ v1, unsigned short* __restrict__ o1,
                                                const float* __restrict__ g2, const float* __restrict__ v2, unsigned short* __restrict__ o2) {
    int o = blockIdx.x & 255, s = blockIdx.x >> 8, tid = threadIdx.x;
    const float* g = s == 0 ? g0 : (s == 1 ? g1 : g2);
    const float* v = s == 0 ? v0 : (s == 1 ? v1 : v2);
    unsigned short* wout = s == 0 ? o0 : (s == 1 ? o1 : o2);
    float x = v[(size_t)o * 256 + tid];
    float q = x * x;
    __shared__ float sm[4];
    #pragma unroll
    for (int d = 32; d; d >>= 1) q += __shfl_down(q, d);
    if ((tid & 63) == 0) sm[tid >> 6] = q;
    __syncthreads();
    float tot = sm[0] + sm[1] + sm[2] + sm[3];
    float scale = g[o] * rsqrtf(tot);
    wout[(size_t)o * 256 + tid] = fbf(x * scale);
}

// ---------------- Wco = wff @ outW  (256x512) ----------------
__global__ __launch_bounds__(256) void wco_k(const unsigned short* __restrict__ wff,
                                             const unsigned short* __restrict__ outWb,
                                             unsigned short* __restrict__ wco) {
    int i = blockIdx.x, tid = threadIdx.x;
    __shared__ float row[256];
    row[tid] = bfb(wff[(size_t)i * 256 + tid]);
    __syncthreads();
    #pragma unroll
    for (int half = 0; half < 2; half++) {
        int k = tid + half * 256;
        float acc = 0.f;
        for (int j = 0; j < 256; j++)
            acc += row[j] * bfb(outWb[(size_t)j * 512 + k]);
        wco[(size_t)i * 512 + k] = fbf(acc);
    }
}

// ---------------- LayerNorm (256-wide), f32 in -> bf16 out ----------------
__global__ __launch_bounds__(256) void ln_k(const float* __restrict__ in,
                                            const float* __restrict__ w,
                                            const float* __restrict__ b,
                                            unsigned short* __restrict__ out) {
    int tok = blockIdx.x, tid = threadIdx.x;
    size_t idx = (size_t)tok * 256 + tid;
    float x = in[idx];
    __shared__ float sm[8];
    float s = x;
    #pragma unroll
    for (int o = 32; o; o >>= 1) s += __shfl_down(s, o);
    if ((tid & 63) == 0) sm[tid >> 6] = s;
    __syncthreads();
    float mean = (sm[0] + sm[1] + sm[2] + sm[3]) * (1.f / 256.f);
    float d = x - mean;
    float q = d * d;
    #pragma unroll
    for (int o = 32; o; o >>= 1) q += __shfl_down(q, o);
    if ((tid & 63) == 0) sm[4 + (tid >> 6)] = q;
    __syncthreads();
    float var = (sm[4] + sm[5] + sm[6] + sm[7]) * (1.f / 256.f);
    out[idx] = fbf(d * rsqrtf(var + LN_EPS) * w[tid] + b[tid]);
}

// ---------------- MFMA GEMM v4b: 2-ahead pipeline + __launch_bounds__(256,2) ----------------
#define BMT 128
#define BNT 128
#define BKT 32
template<int EPI, int NBN>
__global__ __launch_bounds__(256, 2) void gemm_k(const unsigned short* __restrict__ A,
                                                 const unsigned short* __restrict__ Bw,
                                                 int K, int N,
                                                 unsigned short* __restrict__ out_b,
                                                 float* __restrict__ out_f,
                                                 const float* __restrict__ bias,
                                                 const float* __restrict__ res_f,
                                                 unsigned short* __restrict__ out2_b) {
    __shared__ __align__(16) unsigned short smem[16384];
    int tid = threadIdx.x;
    int d = blockIdx.x;
    const int cpx = (256 * NBN) >> 3;
    int logical = (d & 7) * cpx + (d >> 3);
    int bm = logical / NBN;
    int bn = logical % NBN;
    int lane = tid & 63, w = tid >> 6;
    int wr = w >> 1, wc = w & 1;
    int fr = lane & 15, fq = lane >> 4;

    int rsub = w * 16 + (lane >> 2);
    int cl   = ((lane & 3) ^ ((rsub >> 1) & 3)) << 3;
    const unsigned short* gA0 = A  + (size_t)(bm * BMT + rsub)      * K + cl;
    const unsigned short* gA1 = A  + (size_t)(bm * BMT + rsub + 64) * K + cl;
    const unsigned short* gB0 = Bw + (size_t)(bn * BNT + rsub)      * K + cl;
    const unsigned short* gB1 = Bw + (size_t)(bn * BNT + rsub + 64) * K + cl;

    f32x4 acc[4][4];
    #pragma unroll
    for (int m = 0; m < 4; m++)
        #pragma unroll
        for (int n = 0; n < 4; n++)
            #pragma unroll
            for (int r = 0; r < 4; r++) acc[m][n][r] = 0.f;

    auto AS = [&](int buf) { return &smem[buf * 4096]; };
    auto BS = [&](int buf) { return &smem[8192 + buf * 4096]; };
    auto STAGE = [&](int buf, int k0) {
        gld16(gA0 + k0, AS(buf) + w * 512);
        gld16(gA1 + k0, AS(buf) + 2048 + w * 512);
        gld16(gB0 + k0, BS(buf) + w * 512);
        gld16(gB1 + k0, BS(buf) + 2048 + w * 512);
    };

    int nt = K / BKT;
    STAGE(0, 0);
    STAGE(1, BKT);
    for (int t = 0; t < nt; ++t) {
        int buf = t & 1;
        if (t < nt - 1) asm volatile("s_waitcnt vmcnt(4)" ::: "memory");
        else            asm volatile("s_waitcnt vmcnt(0)" ::: "memory");
        __builtin_amdgcn_s_barrier();
        short8 af[4], bf_[4];
        #pragma unroll
        for (int m = 0; m < 4; m++) {
            int ra = wr * 64 + m * 16 + fr;
            af[m] = *(const short8*)&AS(buf)[ra * 32 + ((fq ^ ((ra >> 1) & 3)) << 3)];
        }
        #pragma unroll
        for (int n = 0; n < 4; n++) {
            int rb = wc * 64 + n * 16 + fr;
            bf_[n] = *(const short8*)&BS(buf)[rb * 32 + ((fq ^ ((rb >> 1) & 3)) << 3)];
        }
        asm volatile("s_waitcnt lgkmcnt(0)" ::: "memory");
        __builtin_amdgcn_sched_barrier(0);
        __builtin_amdgcn_s_barrier();
        if (t + 2 < nt) STAGE(buf, (t + 2) * BKT);
        __builtin_amdgcn_s_setprio(1);
        #pragma unroll
        for (int m = 0; m < 4; m++)
            #pragma unroll
            for (int n = 0; n < 4; n++)
                acc[m][n] = __builtin_amdgcn_mfma_f32_16x16x32_bf16(af[m], bf_[n], acc[m][n], 0, 0, 0);
        __builtin_amdgcn_s_setprio(0);
    }
    __builtin_amdgcn_s_barrier();

    if (EPI == 1 && bn == 10) {
        #pragma unroll
        for (int m = 0; m < 4; m++)
            #pragma unroll
            for (int n = 0; n < 4; n++)
                #pragma unroll
                for (int r = 0; r < 4; r++) {
                    int grow = bm * BMT + wr * 64 + m * 16 + fq * 4 + r;
                    int gcol = 1280 + wc * 64 + n * 16 + fr;
                    if (gcol < 1288) {
                        float a2 = acc[m][n][r] + bias[gcol - 1280];
                        out_f[(size_t)grow * 8 + (gcol - 1280)] =
                            a2 > 20.f ? a2 : log1pf(expf(a2));
                    }
                }
    } else if (EPI == 0 || EPI == 1) {
        unsigned short* cb = smem;
        #pragma unroll
        for (int s = 0; s < 2; s++) {
            if (wr == s) {
                #pragma unroll
                for (int m = 0; m < 4; m++)
                    #pragma unroll
                    for (int n = 0; n < 4; n++)
                        #pragma unroll
                        for (int r = 0; r < 4; r++)
                            cb[(m * 16 + fq * 4 + r) * 136 + wc * 64 + n * 16 + fr] =
                                fbf(acc[m][n][r]);
            }
            __syncthreads();
            #pragma unroll
            for (int k = 0; k < 4; k++) {
                int g = k * 256 + tid;
                int row = g >> 4, col = (g & 15) << 3;
                u16x8 v = *(const u16x8*)&cb[row * 136 + col];
                int grow = bm * BMT + s * 64 + row;
                int gc = bn * BNT + col;
                if (EPI == 0) {
                    *(u16x8*)&out_b[(size_t)grow * N + gc] = v;
                } else {
                    if (gc < 512) *(u16x8*)&out_b[(size_t)grow * 512 + gc] = v;
                    else          *(u16x8*)&out2_b[(size_t)grow * 768 + (gc - 512)] = v;
                }
            }
            __syncthreads();
        }
    } else {
        float* fb = (float*)smem;
        #pragma unroll
        for (int s = 0; s < 4; s++) {
            if (wr == (s >> 1)) {
                int mp = s & 1;
                #pragma unroll
                for (int mm = 0; mm < 2; mm++)
                    #pragma unroll
                    for (int n = 0; n < 4; n++)
                        #pragma unroll
                        for (int r = 0; r < 4; r++)
                            fb[(mm * 16 + fq * 4 + r) * 132 + wc * 64 + n * 16 + fr] =
                                acc[mp * 2 + mm][n][r];
            }
            __syncthreads();
            #pragma unroll
            for (int k = 0; k < 4; k++) {
                int g = k * 256 + tid;
                int row = g >> 5, col = (g & 31) << 2;
                f32x4 v = *(const f32x4*)&fb[row * 132 + col];
                int grow = bm * BMT + (s >> 1) * 64 + (s & 1) * 32 + row;
                int gc = bn * BNT + col;
                size_t idx = (size_t)grow * 256 + gc;
                if (EPI == 2) {
                    f32x4 rr = *(const f32x4*)&res_f[idx];
                    f32x4 o;
                    #pragma unroll
                    for (int j = 0; j < 4; j++) o[j] = rr[j] + v[j] + bias[gc + j];
                    *(f32x4*)&out_f[idx] = o;
                } else {
                    u16x4 o;
                    #pragma unroll
                    for (int j = 0; j < 4; j++) {
                        float x = v[j] + bias[gc + j];
                        o[j] = fbf(0.5f * x * (1.f + erff(x * 0.70710678118654752f)));
                    }
                    *(u16x4*)&out_b[idx] = o;
                }
            }
            __syncthreads();
        }
    }
}

// ---------------- halo save ----------------
__global__ __launch_bounds__(256) void halo_k(const unsigned short* __restrict__ xbc,
                                              unsigned short* __restrict__ halo) {
    int blk = blockIdx.x;
    int b = blk / 3, c = blk % 3 + 1;
    int tid = threadIdx.x;
    for (int i = tid; i < 288; i += 256) {
        int j = i / 96, off = (i % 96) * 8;
        size_t tok = (size_t)b * 512 + c * 128 - 3 + j;
        *(u16x8*)&halo[((size_t)(b * 4 + c) * 3 + j) * 768 + off] =
            *(const u16x8*)&xbc[tok * 768 + off];
    }
}

// ---------------- causal depthwise conv4 + bias + silu, PARALLEL (halo) ----------------
__global__ __launch_bounds__(256) void conv_k(unsigned short* xbc,
                                              const unsigned short* __restrict__ halo,
                                              const float* __restrict__ cw,
                                              const float* __restrict__ cb) {
    int b  = blockIdx.y;
    int c  = blockIdx.z;
    int c0 = blockIdx.x * 64;
    int t0 = c * 128;
    int tid = threadIdx.x;
    int cth = tid & 63;
    int rq  = tid >> 6;
    __shared__ unsigned short sraw[131][72];

    int ca = c0 + cth;
    float w0 = cw[ca * 4 + 0], w1 = cw[ca * 4 + 1];
    float w2 = cw[ca * 4 + 2], w3 = cw[ca * 4 + 3];
    float bias = cb[ca];

    if (tid < 192) {
        int j = tid >> 6, cc = tid & 63;
        sraw[j][cc] = (c == 0) ? (unsigned short)0
            : halo[((size_t)(b * 4 + c) * 3 + j) * 768 + c0 + cc];
    }
    for (int idx = tid; idx < 1024; idx += 256) {
        int lt = idx >> 3, cg = idx & 7;
        *(u16x8*)&sraw[3 + lt][cg * 8] =
            *(const u16x8*)&xbc[((size_t)(b * 512 + t0 + lt)) * 768 + c0 + cg * 8];
    }
    __syncthreads();
    #pragma unroll 4
    for (int i = 0; i < 32; i++) {
        int lt = rq + 4 * i;
        float acc = bias
            + bfb(sraw[lt + 0][cth]) * w0
            + bfb(sraw[lt + 1][cth]) * w1
            + bfb(sraw[lt + 2][cth]) * w2
            + bfb(sraw[lt + 3][cth]) * w3;
        acc = acc / (1.f + expf(-acc));
        xbc[((size_t)(b * 512 + t0 + lt)) * 768 + c0 + cth] = fbf(acc);
    }
}

// ---------------- SSD chunked-MFMA scan v5 (r22: prefetch + b-locality swizzle) ----------------
#define CPAD 136
#define TPAD 56
#define TOFF(r) ((((r) >> 4) & 3) << 3)
__global__ __launch_bounds__(256) void ssd_k(const unsigned short* __restrict__ xc,
                                             const float* __restrict__ dts,
                                             const float* __restrict__ A_log,
                                             const float* __restrict__ D_param,
                                             unsigned short* __restrict__ y) {
    __shared__ unsigned short Ct[32][CPAD];
    __shared__ unsigned short Bt[32][CPAD];
    __shared__ unsigned short BtT[128][TPAD];
    __shared__ unsigned short DXT[64][TPAD];
    __shared__ unsigned short LG[32][40];
    __shared__ unsigned short hB[64][CPAD];
    __shared__ unsigned short Yb[32][72];
    __shared__ float scum[32], sdt2[32], sEC[32];
    __shared__ float sET[32][36];

    int d = blockIdx.x;
    int b = (d & 7) | (((d >> 6) & 7) << 3);
    int h = (d >> 3) & 7;
    int tid = threadIdx.x;
    int w = tid >> 6;
    int lane = tid & 63;
    int fr = lane & 15, fq = lane >> 4;

    float A_h = -expf(A_log[h]);
    float D_h = D_param[h];

    f32x4 hacc[8];
    #pragma unroll
    for (int nf = 0; nf < 8; nf++)
        #pragma unroll
        for (int r = 0; r < 4; r++) hacc[nf][r] = 0.f;

    int t  = tid >> 3;
    int e8 = tid & 7;

    u16x8 bv0, bv1, cv0, cv1, xv;
    {
        const unsigned short* row = &xc[((size_t)b * 512 + t) * 768];
        bv0 = *(const u16x8*)&row[512 + e8 * 16];
        bv1 = *(const u16x8*)&row[512 + e8 * 16 + 8];
        cv0 = *(const u16x8*)&row[640 + e8 * 16];
        cv1 = *(const u16x8*)&row[640 + e8 * 16 + 8];
        xv  = *(const u16x8*)&row[h * 64 + e8 * 8];
    }

    for (int c = 0; c < 16; ++c) {
        size_t tok0 = (size_t)b * 512 + c * 32;
        *(u16x8*)&Ct[t][e8 * 16]     = cv0;
        *(u16x8*)&Ct[t][e8 * 16 + 8] = cv1;
        *(u16x8*)&Bt[t][e8 * 16]     = bv0;
        *(u16x8*)&Bt[t][e8 * 16 + 8] = bv1;
        if (tid < 32) {
            float dtv = dts[(tok0 + tid) * 8 + h];
            sdt2[tid] = dtv;
            float la = dtv * A_h;
            #pragma unroll
            for (int dd = 1; dd < 32; dd <<= 1) {
                float up = __shfl_up(la, dd);
                if (lane >= dd) la += up;
            }
            scum[tid] = la;
        }
        __syncthreads();
        float cumQ = scum[31];
        if (tid < 32) sEC[tid] = expf(scum[tid]);
        {
            float dtv = sdt2[t];
            float wgt = expf(cumQ - scum[t]);
            int tof = TOFF(e8 * 16);
            #pragma unroll
            for (int j = 0; j < 8; j++) {
                float dtx = dtv * bfb(xv[j]);
                int rr = e8 * 8 + j;
                DXT[rr][t + TOFF(rr)] = fbf(dtx);
                BtT[e8 * 16 + j][t + tof]     = fbf(wgt * bfb(bv0[j]));
                BtT[e8 * 16 + 8 + j][t + tof] = fbf(wgt * bfb(bv1[j]));
            }
        }
        #pragma unroll
        for (int k = 0; k < 4; k++) {
            int idx = tid * 4 + k;
            int tt = idx >> 5, tq = idx & 31;
            sET[tt][tq] = (tq <= tt) ? expf(scum[tt] - scum[tq]) : 0.f;
        }
        #pragma unroll
        for (int nf = 0; nf < 8; nf++)
            #pragma unroll
            for (int r = 0; r < 4; r++)
                hB[w * 16 + fq * 4 + r][nf * 16 + fr] = fbf(hacc[nf][r]);
        u16x8 nbv0, nbv1, ncv0, ncv1, nxv;
        {
            size_t ptok = (c + 1 < 16) ? (tok0 + 32 + t) : (tok0 + t);
            const unsigned short* row = &xc[ptok * 768];
            nbv0 = *(const u16x8*)&row[512 + e8 * 16];
            nbv1 = *(const u16x8*)&row[512 + e8 * 16 + 8];
            ncv0 = *(const u16x8*)&row[640 + e8 * 16];
            ncv1 = *(const u16x8*)&row[640 + e8 * 16 + 8];
            nxv  = *(const u16x8*)&row[h * 64 + e8 * 8];
        }
        __syncthreads();
        {
            int m = w >> 1, nf = w & 1;
            f32x4 g;
            #pragma unroll
            for (int r = 0; r < 4; r++) g[r] = 0.f;
            #pragma unroll
            for (int ks = 0; ks < 4; ks++) {
                short8 ca = *(const short8*)&Ct[m * 16 + fr][ks * 32 + fq * 8];
                short8 bb = *(const short8*)&Bt[nf * 16 + fr][ks * 32 + fq * 8];
                g = __builtin_amdgcn_mfma_f32_16x16x32_bf16(ca, bb, g, 0, 0, 0);
            }
            #pragma unroll
            for (int r = 0; r < 4; r++) {
                int tt = m * 16 + fq * 4 + r;
                int tq = nf * 16 + fr;
                LG[tt][tq] = fbf(g[r] * sET[tt][tq]);
            }
        }
        __syncthreads();
        f32x4 Yi[2];
        #pragma unroll
        for (int m = 0; m < 2; m++)
            #pragma unroll
            for (int r = 0; r < 4; r++) Yi[m][r] = 0.f;
        #pragma unroll
        for (int ks = 0; ks < 4; ks++) {
            short8 a0 = *(const short8*)&Ct[fr][ks * 32 + fq * 8];
            short8 a1 = *(const short8*)&Ct[16 + fr][ks * 32 + fq * 8];
            short8 hb = *(const short8*)&hB[w * 16 + fr][ks * 32 + fq * 8];
            Yi[0] = __builtin_amdgcn_mfma_f32_16x16x32_bf16(a0, hb, Yi[0], 0, 0, 0);
            Yi[1] = __builtin_amdgcn_mfma_f32_16x16x32_bf16(a1, hb, Yi[1], 0, 0, 0);
        }
        #pragma unroll
        for (int m = 0; m < 2; m++)
            #pragma unroll
            for (int r = 0; r < 4; r++) Yi[m][r] *= sEC[m * 16 + fq * 4 + r];
        {
            int wof = TOFF(w * 16);
            short8 a0 = *(const short8*)&LG[fr][fq * 8];
            short8 a1 = *(const short8*)&LG[16 + fr][fq * 8];
            short8 dx = *(const short8*)&DXT[w * 16 + fr][fq * 8 + wof];
            Yi[0] = __builtin_amdgcn_mfma_f32_16x16x32_bf16(a0, dx, Yi[0], 0, 0, 0);
            Yi[1] = __builtin_amdgcn_mfma_f32_16x16x32_bf16(a1, dx, Yi[1], 0, 0, 0);
        }
        {
            float ecq = sEC[31];
            #pragma unroll
            for (int nf = 0; nf < 8; nf++)
                #pragma unroll
                for (int r = 0; r < 4; r++) hacc[nf][r] *= ecq;
            int wof = TOFF(w * 16);
            short8 ax = *(const short8*)&DXT[w * 16 + fr][fq * 8 + wof];
            #pragma unroll
            for (int nf = 0; nf < 8; nf++) {
                short8 bb = *(const short8*)&BtT[nf * 16 + fr][fq * 8 + TOFF(nf * 16)];
                hacc[nf] = __builtin_amdgcn_mfma_f32_16x16x32_bf16(ax, bb, hacc[nf], 0, 0, 0);
            }
        }
        #pragma unroll
        for (int m = 0; m < 2; m++)
            #pragma unroll
            for (int r = 0; r < 4; r++) {
                int tt = m * 16 + fq * 4 + r;
                Yb[tt][w * 16 + fr] = fbf(Yi[m][r]);
            }
        __syncthreads();
        {
            u16x8 yv = *(const u16x8*)&Yb[t][e8 * 8];
            u16x8 ov;
            #pragma unroll
            for (int j = 0; j < 8; j++)
                ov[j] = fbf(bfb(yv[j]) + D_h * bfb(xv[j]));
            *(u16x8*)&y[(tok0 + t) * 512 + h * 64 + e8 * 8] = ov;
        }
        bv0 = nbv0; bv1 = nbv1; cv0 = ncv0; cv1 = ncv1; xv = nxv;
    }
}

// ---------------- gate (y * silu(zg)) + RMSNorm * w -> bf16 ----------------
__global__ __launch_bounds__(256) void gate_k(const unsigned short* __restrict__ y,
                                              const unsigned short* __restrict__ zg,
                                              const float* __restrict__ nw,
                                              unsigned short* __restrict__ yn) {
    int tok = blockIdx.x, tid = threadIdx.x;
    size_t base = (size_t)tok * 512;
    float gv[2];
    float q = 0.f;
    #pragma unroll
    for (int j = 0; j < 2; j++) {
        int c = tid + j * 256;
        float yy = bfb(y[base + c]);
        float zz = bfb(zg[base + c]);
        float s = zz / (1.f + expf(-zz));
        float t = yy * s;
        gv[j] = t;
        q += t * t;
    }
    __shared__ float sm[4];
    #pragma unroll
    for (int o = 32; o; o >>= 1) q += __shfl_down(q, o);
    if ((tid & 63) == 0) sm[tid >> 6] = q;
    __syncthreads();
    float ms = (sm[0] + sm[1] + sm[2] + sm[3]) * (1.f / 512.f);
    float r = rsqrtf(ms + LN_EPS);
    #pragma unroll
    for (int j = 0; j < 2; j++) {
        int c = tid + j * 256;
        yn[base + c] = fbf(gv[j] * r * nw[c]);
    }
}

extern "C" void kernel_launch(void* const* d_in, const int* in_sizes, int n_in,
                              void* d_out, int out_size, void* d_ws, size_t ws_size,
                              hipStream_t stream) {
    if (n_in < 22) return;
    static const int setup_sizes[22] = {8388608,256,256,329728,3072,768,8,8,8,512,
                                        131072,256,65536,256,256,256,256,65536,256,256,65536,256};
    for (int i = 0; i < 22; i++) if (in_sizes[i] != setup_sizes[i]) return;

    const float* z      = (const float*)d_in[0];
    const float* ln1w   = (const float*)d_in[1];
    const float* ln1b   = (const float*)d_in[2];
    const float* inW    = (const float*)d_in[3];
    const float* convw  = (const float*)d_in[4];
    const float* convb  = (const float*)d_in[5];
    const float* dtb    = (const float*)d_in[6];
    const float* Alog   = (const float*)d_in[7];
    const float* Dp     = (const float*)d_in[8];
    const float* normw  = (const float*)d_in[9];
    const float* outW   = (const float*)d_in[10];
    const float* ffg    = (const float*)d_in[11];
    const float* ffv    = (const float*)d_in[12];
    const float* ffb    = (const float*)d_in[13];
    const float* ln2w   = (const float*)d_in[14];
    const float* ln2b   = (const float*)d_in[15];
    const float* fc1g   = (const float*)d_in[16];
    const float* fc1v   = (const float*)d_in[17];
    const float* fc1b   = (const float*)d_in[18];
    const float* fc2g   = (const float*)d_in[19];
    const float* fc2v   = (const float*)d_in[20];
    const float* fc2b   = (const float*)d_in[21];
    float* out = (float*)d_out;
    (void)out_size;

    char* ws = (char*)d_ws;
    const size_t SLOT_A = (size_t)NTOK * 768 * 2;
    const size_t SLOT_B = (size_t)NTOK * 512 * 2;
    const size_t SLOT_C = (size_t)NTOK * 512 * 2;
    const size_t SLOT_D = (size_t)NTOK * 256 * 2;
    const size_t SLOT_E = (size_t)NTOK * 8 * 4;
    const size_t SLOT_W = (size_t)256 * 256 * 2;
    const size_t SLOT_WI = (size_t)1288 * 256 * 2;
    const size_t SLOT_WO = (size_t)256 * 512 * 2;
    const size_t SLOT_WC = (size_t)256 * 512 * 2;
    const size_t SLOT_H  = (size_t)256 * 3 * 768 * 2;
    char* pA = ws;
    char* pB = pA + SLOT_A;
    char* pC = pB + SLOT_B;
    char* pD = pC + SLOT_C;
    char* pE = pD + SLOT_D;
    char* pW = pE + SLOT_E;
    char* pWI = pW + 3 * SLOT_W;
    char* pWO = pWI + SLOT_WI;
    char* pWC = pWO + SLOT_WO;
    char* pH  = pWC + SLOT_WC;
    size_t need = SLOT_A + SLOT_B + SLOT_C + SLOT_D + SLOT_E + 3 * SLOT_W + SLOT_WI + SLOT_WO + SLOT_WC + SLOT_H;
    if (ws_size < need) return;

    unsigned short* xbc = (unsigned short*)pA;
    unsigned short* yn  = (unsigned short*)pA;
    unsigned short* t2  = (unsigned short*)(pA + (size_t)NTOK * 512 * 2);
    unsigned short* y   = (unsigned short*)pB;
    float*          z2  = (float*)pB;
    unsigned short* zgb = (unsigned short*)pC;
    unsigned short* u   = (unsigned short*)pD;
    unsigned short* h1  = (unsigned short*)pD;
    float*          dts = (float*)pE;
    unsigned short* wff  = (unsigned short*)pW;
    unsigned short* wfc1 = (unsigned short*)(pW + SLOT_W);
    unsigned short* wfc2 = (unsigned short*)(pW + 2 * SLOT_W);
    unsigned short* inWb = (unsigned short*)pWI;
    unsigned short* outWb = (unsigned short*)pWO;
    unsigned short* wco  = (unsigned short*)pWC;
    unsigned short* halo = (unsigned short*)pH;

    cvt2_k<<<(1288 * 256 + 131072 + 255) / 256, 256, 0, stream>>>(inW, inWb, 1288 * 256,
                                                                  outW, outWb, 131072);
    wnorm3_k<<<768, 256, 0, stream>>>(ffg, ffv, wff, fc1g, fc1v, wfc1, fc2g, fc2v, wfc2);
    wco_k<<<256, 256, 0, stream>>>(wff, outWb, wco);
    ln_k<<<NTOK, 256, 0, stream>>>(z, ln1w, ln1b, u);
    gemm_k<1, 11><<<256 * 11, 256, 0, stream>>>(u, inWb, 256, 1288,
                                                zgb, dts, dtb, nullptr, xbc);
    halo_k<<<192, 256, 0, stream>>>(xbc, halo);
    conv_k<<<dim3(12, 64, 4), 256, 0, stream>>>(xbc, halo, convw, convb);
    ssd_k<<<512, 256, 0, stream>>>(xbc, dts, Alog, Dp, y);
    gate_k<<<NTOK, 256, 0, stream>>>(y, zgb, normw, yn);
    gemm_k<2, 2><<<256 * 2, 256, 0, stream>>>(yn, wco, 512, 256,
                                              nullptr, z2, ffb, z, nullptr);
    ln_k<<<NTOK, 256, 0, stream>>>(z2, ln2w, ln2b, t2);
    gemm_k<3, 2><<<256 * 2, 256, 0, stream>>>(t2, wfc1, 256, 256,
                                              h1, nullptr, fc1b, nullptr, nullptr);
    gemm_k<2, 2><<<256 * 2, 256, 0, stream>>>(h1, wfc2, 256, 256,
                                              nullptr, out, fc2b, z2, nullptr);
}

// Round 26
// 288.530 us; speedup vs baseline: 1.1598x; 1.0062x over previous
//
#include <hip/hip_runtime.h>
#include <stdint.h>
#include <math.h>

#define EMB       256
#define D_INNER   512
#define HEADDIM   64
#define NHEADS    8
#define DSTATE    128
#define DCONV     4
#define CONV_DIM  768
#define LN_EPS    1e-5f
#define NBATCH    64
#define SEQLEN    512
#define NTOK      (NBATCH*SEQLEN)   // 32768

typedef __attribute__((ext_vector_type(8))) short          short8;
typedef __attribute__((ext_vector_type(8))) unsigned short u16x8;
typedef __attribute__((ext_vector_type(4))) unsigned short u16x4;
typedef __attribute__((ext_vector_type(4))) float          f32x4;

__device__ __forceinline__ float bfb(unsigned short u) {
    union { unsigned int i; float f; } x; x.i = ((unsigned int)u) << 16; return x.f;
}
__device__ __forceinline__ unsigned short fbf(float f) {
    union { float f; unsigned int i; } x; x.f = f;
    unsigned int i = x.i;
    unsigned int lsb = (i >> 16) & 1u;
    i += 0x7fffu + lsb;
    return (unsigned short)(i >> 16);
}

// async global->LDS 16B
__device__ __forceinline__ void gld16(const unsigned short* g, unsigned short* l) {
    __builtin_amdgcn_global_load_lds((const __attribute__((address_space(1))) void*)g,
                                     (__attribute__((address_space(3))) void*)l, 16, 0, 0);
}

// ---------------- merged f32->bf16 converts (inW | outW) ----------------
__global__ __launch_bounds__(256) void cvt2_k(const float* __restrict__ a, unsigned short* __restrict__ oa, int na,
                                              const float* __restrict__ b, unsigned short* __restrict__ ob, int nb) {
    int i = blockIdx.x * 256 + threadIdx.x;
    if (i < na) oa[i] = fbf(a[i]);
    else { i -= na; if (i < nb) ob[i] = fbf(b[i]); }
}

// ---------------- merged weight-norm x3 ----------------
__global__ __launch_bounds__(256) void wnorm3_k(const float* __restrict__ g0, const float* __restrict__ v0, unsigned short* __restrict__ o0,
                                                const float* __restrict__ g1, const float* __restrict__ v1, unsigned short* __restrict__ o1,
                                                const float* __restrict__ g2, const float* __restrict__ v2, unsigned short* __restrict__ o2) {
    int o = blockIdx.x & 255, s = blockIdx.x >> 8, tid = threadIdx.x;
    const float* g = s == 0 ? g0 : (s == 1 ? g1 : g2);
    const float* v = s == 0 ? v0 : (s == 1 ? v1 : v2);
    unsigned short* wout = s == 0 ? o0 : (s == 1 ? o1 : o2);
    float x = v[(size_t)o * 256 + tid];
    float q = x * x;
    __shared__ float sm[4];
    #pragma unroll
    for (int d = 32; d; d >>= 1) q += __shfl_down(q, d);
    if ((tid & 63) == 0) sm[tid >> 6] = q;
    __syncthreads();
    float tot = sm[0] + sm[1] + sm[2] + sm[3];
    float scale = g[o] * rsqrtf(tot);
    wout[(size_t)o * 256 + tid] = fbf(x * scale);
}

// ---------------- Wco = wff @ outW  (256x512) ----------------
__global__ __launch_bounds__(256) void wco_k(const unsigned short* __restrict__ wff,
                                             const unsigned short* __restrict__ outWb,
                                             unsigned short* __restrict__ wco) {
    int i = blockIdx.x, tid = threadIdx.x;
    __shared__ float row[256];
    row[tid] = bfb(wff[(size_t)i * 256 + tid]);
    __syncthreads();
    #pragma unroll
    for (int half = 0; half < 2; half++) {
        int k = tid + half * 256;
        float acc = 0.f;
        for (int j = 0; j < 256; j++)
            acc += row[j] * bfb(outWb[(size_t)j * 512 + k]);
        wco[(size_t)i * 512 + k] = fbf(acc);
    }
}

// ---------------- LayerNorm (256-wide), f32 in -> bf16 out ----------------
__global__ __launch_bounds__(256) void ln_k(const float* __restrict__ in,
                                            const float* __restrict__ w,
                                            const float* __restrict__ b,
                                            unsigned short* __restrict__ out) {
    int tok = blockIdx.x, tid = threadIdx.x;
    size_t idx = (size_t)tok * 256 + tid;
    float x = in[idx];
    __shared__ float sm[8];
    float s = x;
    #pragma unroll
    for (int o = 32; o; o >>= 1) s += __shfl_down(s, o);
    if ((tid & 63) == 0) sm[tid >> 6] = s;
    __syncthreads();
    float mean = (sm[0] + sm[1] + sm[2] + sm[3]) * (1.f / 256.f);
    float d = x - mean;
    float q = d * d;
    #pragma unroll
    for (int o = 32; o; o >>= 1) q += __shfl_down(q, o);
    if ((tid & 63) == 0) sm[4 + (tid >> 6)] = q;
    __syncthreads();
    float var = (sm[4] + sm[5] + sm[6] + sm[7]) * (1.f / 256.f);
    out[idx] = fbf(d * rsqrtf(var + LN_EPS) * w[tid] + b[tid]);
}

// ---------------- MFMA GEMM v4b: 2-ahead pipeline + __launch_bounds__(256,2) ----------------
#define BMT 128
#define BNT 128
#define BKT 32
template<int EPI, int NBN>
__global__ __launch_bounds__(256, 2) void gemm_k(const unsigned short* __restrict__ A,
                                                 const unsigned short* __restrict__ Bw,
                                                 int K, int N,
                                                 unsigned short* __restrict__ out_b,
                                                 float* __restrict__ out_f,
                                                 const float* __restrict__ bias,
                                                 const float* __restrict__ res_f,
                                                 unsigned short* __restrict__ out2_b) {
    __shared__ __align__(16) unsigned short smem[16384];
    int tid = threadIdx.x;
    int d = blockIdx.x;
    const int cpx = (256 * NBN) >> 3;
    int logical = (d & 7) * cpx + (d >> 3);
    int bm = logical / NBN;
    int bn = logical % NBN;
    int lane = tid & 63, w = tid >> 6;
    int wr = w >> 1, wc = w & 1;
    int fr = lane & 15, fq = lane >> 4;

    int rsub = w * 16 + (lane >> 2);
    int cl   = ((lane & 3) ^ ((rsub >> 1) & 3)) << 3;
    const unsigned short* gA0 = A  + (size_t)(bm * BMT + rsub)      * K + cl;
    const unsigned short* gA1 = A  + (size_t)(bm * BMT + rsub + 64) * K + cl;
    const unsigned short* gB0 = Bw + (size_t)(bn * BNT + rsub)      * K + cl;
    const unsigned short* gB1 = Bw + (size_t)(bn * BNT + rsub + 64) * K + cl;

    f32x4 acc[4][4];
    #pragma unroll
    for (int m = 0; m < 4; m++)
        #pragma unroll
        for (int n = 0; n < 4; n++)
            #pragma unroll
            for (int r = 0; r < 4; r++) acc[m][n][r] = 0.f;

    auto AS = [&](int buf) { return &smem[buf * 4096]; };
    auto BS = [&](int buf) { return &smem[8192 + buf * 4096]; };
    auto STAGE = [&](int buf, int k0) {
        gld16(gA0 + k0, AS(buf) + w * 512);
        gld16(gA1 + k0, AS(buf) + 2048 + w * 512);
        gld16(gB0 + k0, BS(buf) + w * 512);
        gld16(gB1 + k0, BS(buf) + 2048 + w * 512);
    };

    int nt = K / BKT;
    STAGE(0, 0);
    STAGE(1, BKT);
    for (int t = 0; t < nt; ++t) {
        int buf = t & 1;
        if (t < nt - 1) asm volatile("s_waitcnt vmcnt(4)" ::: "memory");
        else            asm volatile("s_waitcnt vmcnt(0)" ::: "memory");
        __builtin_amdgcn_s_barrier();
        short8 af[4], bf_[4];
        #pragma unroll
        for (int m = 0; m < 4; m++) {
            int ra = wr * 64 + m * 16 + fr;
            af[m] = *(const short8*)&AS(buf)[ra * 32 + ((fq ^ ((ra >> 1) & 3)) << 3)];
        }
        #pragma unroll
        for (int n = 0; n < 4; n++) {
            int rb = wc * 64 + n * 16 + fr;
            bf_[n] = *(const short8*)&BS(buf)[rb * 32 + ((fq ^ ((rb >> 1) & 3)) << 3)];
        }
        asm volatile("s_waitcnt lgkmcnt(0)" ::: "memory");
        __builtin_amdgcn_sched_barrier(0);
        __builtin_amdgcn_s_barrier();
        if (t + 2 < nt) STAGE(buf, (t + 2) * BKT);
        __builtin_amdgcn_s_setprio(1);
        #pragma unroll
        for (int m = 0; m < 4; m++)
            #pragma unroll
            for (int n = 0; n < 4; n++)
                acc[m][n] = __builtin_amdgcn_mfma_f32_16x16x32_bf16(af[m], bf_[n], acc[m][n], 0, 0, 0);
        __builtin_amdgcn_s_setprio(0);
    }
    __builtin_amdgcn_s_barrier();

    if (EPI == 1 && bn == 10) {
        #pragma unroll
        for (int m = 0; m < 4; m++)
            #pragma unroll
            for (int n = 0; n < 4; n++)
                #pragma unroll
                for (int r = 0; r < 4; r++) {
                    int grow = bm * BMT + wr * 64 + m * 16 + fq * 4 + r;
                    int gcol = 1280 + wc * 64 + n * 16 + fr;
                    if (gcol < 1288) {
                        float a2 = acc[m][n][r] + bias[gcol - 1280];
                        out_f[(size_t)grow * 8 + (gcol - 1280)] =
                            a2 > 20.f ? a2 : log1pf(expf(a2));
                    }
                }
    } else if (EPI == 0 || EPI == 1) {
        unsigned short* cb = smem;
        #pragma unroll
        for (int s = 0; s < 2; s++) {
            if (wr == s) {
                #pragma unroll
                for (int m = 0; m < 4; m++)
                    #pragma unroll
                    for (int n = 0; n < 4; n++)
                        #pragma unroll
                        for (int r = 0; r < 4; r++)
                            cb[(m * 16 + fq * 4 + r) * 136 + wc * 64 + n * 16 + fr] =
                                fbf(acc[m][n][r]);
            }
            __syncthreads();
            #pragma unroll
            for (int k = 0; k < 4; k++) {
                int g = k * 256 + tid;
                int row = g >> 4, col = (g & 15) << 3;
                u16x8 v = *(const u16x8*)&cb[row * 136 + col];
                int grow = bm * BMT + s * 64 + row;
                int gc = bn * BNT + col;
                if (EPI == 0) {
                    *(u16x8*)&out_b[(size_t)grow * N + gc] = v;
                } else {
                    if (gc < 512) *(u16x8*)&out_b[(size_t)grow * 512 + gc] = v;
                    else          *(u16x8*)&out2_b[(size_t)grow * 768 + (gc - 512)] = v;
                }
            }
            __syncthreads();
        }
    } else {
        float* fb = (float*)smem;
        #pragma unroll
        for (int s = 0; s < 4; s++) {
            if (wr == (s >> 1)) {
                int mp = s & 1;
                #pragma unroll
                for (int mm = 0; mm < 2; mm++)
                    #pragma unroll
                    for (int n = 0; n < 4; n++)
                        #pragma unroll
                        for (int r = 0; r < 4; r++)
                            fb[(mm * 16 + fq * 4 + r) * 132 + wc * 64 + n * 16 + fr] =
                                acc[mp * 2 + mm][n][r];
            }
            __syncthreads();
            #pragma unroll
            for (int k = 0; k < 4; k++) {
                int g = k * 256 + tid;
                int row = g >> 5, col = (g & 31) << 2;
                f32x4 v = *(const f32x4*)&fb[row * 132 + col];
                int grow = bm * BMT + (s >> 1) * 64 + (s & 1) * 32 + row;
                int gc = bn * BNT + col;
                size_t idx = (size_t)grow * 256 + gc;
                if (EPI == 2) {
                    f32x4 rr = *(const f32x4*)&res_f[idx];
                    f32x4 o;
                    #pragma unroll
                    for (int j = 0; j < 4; j++) o[j] = rr[j] + v[j] + bias[gc + j];
                    *(f32x4*)&out_f[idx] = o;
                } else {
                    u16x4 o;
                    #pragma unroll
                    for (int j = 0; j < 4; j++) {
                        float x = v[j] + bias[gc + j];
                        o[j] = fbf(0.5f * x * (1.f + erff(x * 0.70710678118654752f)));
                    }
                    *(u16x4*)&out_b[idx] = o;
                }
            }
            __syncthreads();
        }
    }
}

// ---------------- halo save ----------------
__global__ __launch_bounds__(256) void halo_k(const unsigned short* __restrict__ xbc,
                                              unsigned short* __restrict__ halo) {
    int blk = blockIdx.x;
    int b = blk / 3, c = blk % 3 + 1;
    int tid = threadIdx.x;
    for (int i = tid; i < 288; i += 256) {
        int j = i / 96, off = (i % 96) * 8;
        size_t tok = (size_t)b * 512 + c * 128 - 3 + j;
        *(u16x8*)&halo[((size_t)(b * 4 + c) * 3 + j) * 768 + off] =
            *(const u16x8*)&xbc[tok * 768 + off];
    }
}

// ---------------- causal depthwise conv4 + bias + silu, PARALLEL (halo) ----------------
__global__ __launch_bounds__(256) void conv_k(unsigned short* xbc,
                                              const unsigned short* __restrict__ halo,
                                              const float* __restrict__ cw,
                                              const float* __restrict__ cb) {
    int b  = blockIdx.y;
    int c  = blockIdx.z;
    int c0 = blockIdx.x * 64;
    int t0 = c * 128;
    int tid = threadIdx.x;
    int cth = tid & 63;
    int rq  = tid >> 6;
    __shared__ unsigned short sraw[131][72];

    int ca = c0 + cth;
    float w0 = cw[ca * 4 + 0], w1 = cw[ca * 4 + 1];
    float w2 = cw[ca * 4 + 2], w3 = cw[ca * 4 + 3];
    float bias = cb[ca];

    if (tid < 192) {
        int j = tid >> 6, cc = tid & 63;
        sraw[j][cc] = (c == 0) ? (unsigned short)0
            : halo[((size_t)(b * 4 + c) * 3 + j) * 768 + c0 + cc];
    }
    for (int idx = tid; idx < 1024; idx += 256) {
        int lt = idx >> 3, cg = idx & 7;
        *(u16x8*)&sraw[3 + lt][cg * 8] =
            *(const u16x8*)&xbc[((size_t)(b * 512 + t0 + lt)) * 768 + c0 + cg * 8];
    }
    __syncthreads();
    #pragma unroll 4
    for (int i = 0; i < 32; i++) {
        int lt = rq + 4 * i;
        float acc = bias
            + bfb(sraw[lt + 0][cth]) * w0
            + bfb(sraw[lt + 1][cth]) * w1
            + bfb(sraw[lt + 2][cth]) * w2
            + bfb(sraw[lt + 3][cth]) * w3;
        acc = acc / (1.f + expf(-acc));
        xbc[((size_t)(b * 512 + t0 + lt)) * 768 + c0 + cth] = fbf(acc);
    }
}

// ---------------- SSD chunked-MFMA scan v6: sET table removed, LG fused into Phase B ----
// Per-lane decay expf(scum[tt]-scum[tq]) computed directly (same formula/inputs as the
// old sET table -> bit-identical); removes one barrier per chunk (4 -> 3).
#define CPAD 136
#define TPAD 56
#define TOFF(r) ((((r) >> 4) & 3) << 3)
__global__ __launch_bounds__(256) void ssd_k(const unsigned short* __restrict__ xc,
                                             const float* __restrict__ dts,
                                             const float* __restrict__ A_log,
                                             const float* __restrict__ D_param,
                                             unsigned short* __restrict__ y) {
    __shared__ unsigned short Ct[32][CPAD];
    __shared__ unsigned short Bt[32][CPAD];
    __shared__ unsigned short BtT[128][TPAD];
    __shared__ unsigned short DXT[64][TPAD];
    __shared__ unsigned short LG[32][40];
    __shared__ unsigned short hB[64][CPAD];
    __shared__ unsigned short Yb[32][72];
    __shared__ float scum[32], sdt2[32], sEC[32];

    int d = blockIdx.x;
    int b = (d & 7) | (((d >> 6) & 7) << 3);
    int h = (d >> 3) & 7;
    int tid = threadIdx.x;
    int w = tid >> 6;
    int lane = tid & 63;
    int fr = lane & 15, fq = lane >> 4;

    float A_h = -expf(A_log[h]);
    float D_h = D_param[h];

    f32x4 hacc[8];
    #pragma unroll
    for (int nf = 0; nf < 8; nf++)
        #pragma unroll
        for (int r = 0; r < 4; r++) hacc[nf][r] = 0.f;

    int t  = tid >> 3;
    int e8 = tid & 7;

    u16x8 bv0, bv1, cv0, cv1, xv;
    {
        const unsigned short* row = &xc[((size_t)b * 512 + t) * 768];
        bv0 = *(const u16x8*)&row[512 + e8 * 16];
        bv1 = *(const u16x8*)&row[512 + e8 * 16 + 8];
        cv0 = *(const u16x8*)&row[640 + e8 * 16];
        cv1 = *(const u16x8*)&row[640 + e8 * 16 + 8];
        xv  = *(const u16x8*)&row[h * 64 + e8 * 8];
    }

    for (int c = 0; c < 16; ++c) {
        size_t tok0 = (size_t)b * 512 + c * 32;
        // ---- Phase A: LDS writes from registers + cum prefix ----
        *(u16x8*)&Ct[t][e8 * 16]     = cv0;
        *(u16x8*)&Ct[t][e8 * 16 + 8] = cv1;
        *(u16x8*)&Bt[t][e8 * 16]     = bv0;
        *(u16x8*)&Bt[t][e8 * 16 + 8] = bv1;
        if (tid < 32) {
            float dtv = dts[(tok0 + tid) * 8 + h];
            sdt2[tid] = dtv;
            float la = dtv * A_h;
            #pragma unroll
            for (int dd = 1; dd < 32; dd <<= 1) {
                float up = __shfl_up(la, dd);
                if (lane >= dd) la += up;
            }
            scum[tid] = la;
        }
        __syncthreads();                       // barrier 1: Ct/Bt/scum ready
        float cumQ = scum[31];
        // ---- Phase B: weighted staging + h snapshot + LG (fused) + prefetch ----
        if (tid < 32) sEC[tid] = expf(scum[tid]);
        {
            float dtv = sdt2[t];
            float wgt = expf(cumQ - scum[t]);
            int tof = TOFF(e8 * 16);
            #pragma unroll
            for (int j = 0; j < 8; j++) {
                float dtx = dtv * bfb(xv[j]);
                int rr = e8 * 8 + j;
                DXT[rr][t + TOFF(rr)] = fbf(dtx);
                BtT[e8 * 16 + j][t + tof]     = fbf(wgt * bfb(bv0[j]));
                BtT[e8 * 16 + 8 + j][t + tof] = fbf(wgt * bfb(bv1[j]));
            }
        }
        #pragma unroll
        for (int nf = 0; nf < 8; nf++)
            #pragma unroll
            for (int r = 0; r < 4; r++)
                hB[w * 16 + fq * 4 + r][nf * 16 + fr] = fbf(hacc[nf][r]);
        // LG quadrant (reads Ct/Bt ready since barrier 1; per-lane decay from scum)
        {
            int m = w >> 1, nf = w & 1;
            f32x4 g;
            #pragma unroll
            for (int r = 0; r < 4; r++) g[r] = 0.f;
            #pragma unroll
            for (int ks = 0; ks < 4; ks++) {
                short8 ca = *(const short8*)&Ct[m * 16 + fr][ks * 32 + fq * 8];
                short8 bb = *(const short8*)&Bt[nf * 16 + fr][ks * 32 + fq * 8];
                g = __builtin_amdgcn_mfma_f32_16x16x32_bf16(ca, bb, g, 0, 0, 0);
            }
            int tq = nf * 16 + fr;
            float sq = scum[tq];
            #pragma unroll
            for (int r = 0; r < 4; r++) {
                int tt = m * 16 + fq * 4 + r;
                float dec = (tq <= tt) ? expf(scum[tt] - sq) : 0.f;
                LG[tt][tq] = fbf(g[r] * dec);
            }
        }
        // prefetch next chunk into registers
        u16x8 nbv0, nbv1, ncv0, ncv1, nxv;
        {
            size_t ptok = (c + 1 < 16) ? (tok0 + 32 + t) : (tok0 + t);
            const unsigned short* row = &xc[ptok * 768];
            nbv0 = *(const u16x8*)&row[512 + e8 * 16];
            nbv1 = *(const u16x8*)&row[512 + e8 * 16 + 8];
            ncv0 = *(const u16x8*)&row[640 + e8 * 16];
            ncv1 = *(const u16x8*)&row[640 + e8 * 16 + 8];
            nxv  = *(const u16x8*)&row[h * 64 + e8 * 8];
        }
        __syncthreads();                       // barrier 2: DXT/BtT/hB/LG ready
        // ---- Phase D: Y and h update ----
        f32x4 Yi[2];
        #pragma unroll
        for (int m = 0; m < 2; m++)
            #pragma unroll
            for (int r = 0; r < 4; r++) Yi[m][r] = 0.f;
        #pragma unroll
        for (int ks = 0; ks < 4; ks++) {
            short8 a0 = *(const short8*)&Ct[fr][ks * 32 + fq * 8];
            short8 a1 = *(const short8*)&Ct[16 + fr][ks * 32 + fq * 8];
            short8 hb = *(const short8*)&hB[w * 16 + fr][ks * 32 + fq * 8];
            Yi[0] = __builtin_amdgcn_mfma_f32_16x16x32_bf16(a0, hb, Yi[0], 0, 0, 0);
            Yi[1] = __builtin_amdgcn_mfma_f32_16x16x32_bf16(a1, hb, Yi[1], 0, 0, 0);
        }
        #pragma unroll
        for (int m = 0; m < 2; m++)
            #pragma unroll
            for (int r = 0; r < 4; r++) Yi[m][r] *= sEC[m * 16 + fq * 4 + r];
        {
            int wof = TOFF(w * 16);
            short8 a0 = *(const short8*)&LG[fr][fq * 8];
            short8 a1 = *(const short8*)&LG[16 + fr][fq * 8];
            short8 dx = *(const short8*)&DXT[w * 16 + fr][fq * 8 + wof];
            Yi[0] = __builtin_amdgcn_mfma_f32_16x16x32_bf16(a0, dx, Yi[0], 0, 0, 0);
            Yi[1] = __builtin_amdgcn_mfma_f32_16x16x32_bf16(a1, dx, Yi[1], 0, 0, 0);
        }
        {
            float ecq = sEC[31];
            #pragma unroll
            for (int nf = 0; nf < 8; nf++)
                #pragma unroll
                for (int r = 0; r < 4; r++) hacc[nf][r] *= ecq;
            int wof = TOFF(w * 16);
            short8 ax = *(const short8*)&DXT[w * 16 + fr][fq * 8 + wof];
            #pragma unroll
            for (int nf = 0; nf < 8; nf++) {
                short8 bb = *(const short8*)&BtT[nf * 16 + fr][fq * 8 + TOFF(nf * 16)];
                hacc[nf] = __builtin_amdgcn_mfma_f32_16x16x32_bf16(ax, bb, hacc[nf], 0, 0, 0);
            }
        }
        #pragma unroll
        for (int m = 0; m < 2; m++)
            #pragma unroll
            for (int r = 0; r < 4; r++) {
                int tt = m * 16 + fq * 4 + r;
                Yb[tt][w * 16 + fr] = fbf(Yi[m][r]);
            }
        __syncthreads();                       // barrier 3: Yb ready
        // ---- Phase E: coalesced Y store, + D*x from registers ----
        {
            u16x8 yv = *(const u16x8*)&Yb[t][e8 * 8];
            u16x8 ov;
            #pragma unroll
            for (int j = 0; j < 8; j++)
                ov[j] = fbf(bfb(yv[j]) + D_h * bfb(xv[j]));
            *(u16x8*)&y[(tok0 + t) * 512 + h * 64 + e8 * 8] = ov;
        }
        bv0 = nbv0; bv1 = nbv1; cv0 = ncv0; cv1 = ncv1; xv = nxv;
    }
}

// ---------------- gate (y * silu(zg)) + RMSNorm * w -> bf16 ----------------
__global__ __launch_bounds__(256) void gate_k(const unsigned short* __restrict__ y,
                                              const unsigned short* __restrict__ zg,
                                              const float* __restrict__ nw,
                                              unsigned short* __restrict__ yn) {
    int tok = blockIdx.x, tid = threadIdx.x;
    size_t base = (size_t)tok * 512;
    float gv[2];
    float q = 0.f;
    #pragma unroll
    for (int j = 0; j < 2; j++) {
        int c = tid + j * 256;
        float yy = bfb(y[base + c]);
        float zz = bfb(zg[base + c]);
        float s = zz / (1.f + expf(-zz));
        float t = yy * s;
        gv[j] = t;
        q += t * t;
    }
    __shared__ float sm[4];
    #pragma unroll
    for (int o = 32; o; o >>= 1) q += __shfl_down(q, o);
    if ((tid & 63) == 0) sm[tid >> 6] = q;
    __syncthreads();
    float ms = (sm[0] + sm[1] + sm[2] + sm[3]) * (1.f / 512.f);
    float r = rsqrtf(ms + LN_EPS);
    #pragma unroll
    for (int j = 0; j < 2; j++) {
        int c = tid + j * 256;
        yn[base + c] = fbf(gv[j] * r * nw[c]);
    }
}

extern "C" void kernel_launch(void* const* d_in, const int* in_sizes, int n_in,
                              void* d_out, int out_size, void* d_ws, size_t ws_size,
                              hipStream_t stream) {
    if (n_in < 22) return;
    static const int setup_sizes[22] = {8388608,256,256,329728,3072,768,8,8,8,512,
                                        131072,256,65536,256,256,256,256,65536,256,256,65536,256};
    for (int i = 0; i < 22; i++) if (in_sizes[i] != setup_sizes[i]) return;

    const float* z      = (const float*)d_in[0];
    const float* ln1w   = (const float*)d_in[1];
    const float* ln1b   = (const float*)d_in[2];
    const float* inW    = (const float*)d_in[3];
    const float* convw  = (const float*)d_in[4];
    const float* convb  = (const float*)d_in[5];
    const float* dtb    = (const float*)d_in[6];
    const float* Alog   = (const float*)d_in[7];
    const float* Dp     = (const float*)d_in[8];
    const float* normw  = (const float*)d_in[9];
    const float* outW   = (const float*)d_in[10];
    const float* ffg    = (const float*)d_in[11];
    const float* ffv    = (const float*)d_in[12];
    const float* ffb    = (const float*)d_in[13];
    const float* ln2w   = (const float*)d_in[14];
    const float* ln2b   = (const float*)d_in[15];
    const float* fc1g   = (const float*)d_in[16];
    const float* fc1v   = (const float*)d_in[17];
    const float* fc1b   = (const float*)d_in[18];
    const float* fc2g   = (const float*)d_in[19];
    const float* fc2v   = (const float*)d_in[20];
    const float* fc2b   = (const float*)d_in[21];
    float* out = (float*)d_out;
    (void)out_size;

    char* ws = (char*)d_ws;
    const size_t SLOT_A = (size_t)NTOK * 768 * 2;
    const size_t SLOT_B = (size_t)NTOK * 512 * 2;
    const size_t SLOT_C = (size_t)NTOK * 512 * 2;
    const size_t SLOT_D = (size_t)NTOK * 256 * 2;
    const size_t SLOT_E = (size_t)NTOK * 8 * 4;
    const size_t SLOT_W = (size_t)256 * 256 * 2;
    const size_t SLOT_WI = (size_t)1288 * 256 * 2;
    const size_t SLOT_WO = (size_t)256 * 512 * 2;
    const size_t SLOT_WC = (size_t)256 * 512 * 2;
    const size_t SLOT_H  = (size_t)256 * 3 * 768 * 2;
    char* pA = ws;
    char* pB = pA + SLOT_A;
    char* pC = pB + SLOT_B;
    char* pD = pC + SLOT_C;
    char* pE = pD + SLOT_D;
    char* pW = pE + SLOT_E;
    char* pWI = pW + 3 * SLOT_W;
    char* pWO = pWI + SLOT_WI;
    char* pWC = pWO + SLOT_WO;
    char* pH  = pWC + SLOT_WC;
    size_t need = SLOT_A + SLOT_B + SLOT_C + SLOT_D + SLOT_E + 3 * SLOT_W + SLOT_WI + SLOT_WO + SLOT_WC + SLOT_H;
    if (ws_size < need) return;

    unsigned short* xbc = (unsigned short*)pA;
    unsigned short* yn  = (unsigned short*)pA;
    unsigned short* t2  = (unsigned short*)(pA + (size_t)NTOK * 512 * 2);
    unsigned short* y   = (unsigned short*)pB;
    float*          z2  = (float*)pB;
    unsigned short* zgb = (unsigned short*)pC;
    unsigned short* u   = (unsigned short*)pD;
    unsigned short* h1  = (unsigned short*)pD;
    float*          dts = (float*)pE;
    unsigned short* wff  = (unsigned short*)pW;
    unsigned short* wfc1 = (unsigned short*)(pW + SLOT_W);
    unsigned short* wfc2 = (unsigned short*)(pW + 2 * SLOT_W);
    unsigned short* inWb = (unsigned short*)pWI;
    unsigned short* outWb = (unsigned short*)pWO;
    unsigned short* wco  = (unsigned short*)pWC;
    unsigned short* halo = (unsigned short*)pH;

    cvt2_k<<<(1288 * 256 + 131072 + 255) / 256, 256, 0, stream>>>(inW, inWb, 1288 * 256,
                                                                  outW, outWb, 131072);
    wnorm3_k<<<768, 256, 0, stream>>>(ffg, ffv, wff, fc1g, fc1v, wfc1, fc2g, fc2v, wfc2);
    wco_k<<<256, 256, 0, stream>>>(wff, outWb, wco);
    ln_k<<<NTOK, 256, 0, stream>>>(z, ln1w, ln1b, u);
    gemm_k<1, 11><<<256 * 11, 256, 0, stream>>>(u, inWb, 256, 1288,
                                                zgb, dts, dtb, nullptr, xbc);
    halo_k<<<192, 256, 0, stream>>>(xbc, halo);
    conv_k<<<dim3(12, 64, 4), 256, 0, stream>>>(xbc, halo, convw, convb);
    ssd_k<<<512, 256, 0, stream>>>(xbc, dts, Alog, Dp, y);
    gate_k<<<NTOK, 256, 0, stream>>>(y, zgb, normw, yn);
    gemm_k<2, 2><<<256 * 2, 256, 0, stream>>>(yn, wco, 512, 256,
                                              nullptr, z2, ffb, z, nullptr);
    ln_k<<<NTOK, 256, 0, stream>>>(z2, ln2w, ln2b, t2);
    gemm_k<3, 2><<<256 * 2, 256, 0, stream>>>(t2, wfc1, 256, 256,
                                              h1, nullptr, fc1b, nullptr, nullptr);
    gemm_k<2, 2><<<256 * 2, 256, 0, stream>>>(h1, wfc2, 256, 256,
                                              nullptr, out, fc2b, z2, nullptr);
}